// Round 4
// baseline (133.760 us; speedup 1.0000x reference)
//
#include <hip/hip_runtime.h>
#include <hip/hip_bf16.h>
#include <math.h>

// Problem constants (N, C, H, W) = (4, 256, 64, 64), out_C = 256, FS=3, pad=1, stride=1
#define NB     4
#define CIN    256
#define HH     64
#define WW     64
#define OUTC   256
#define K2     9
#define KTOT   2304                // CIN * K2
#define HWSZ   4096                // HH * WW
#define NSTEPS 72                  // KTOT / 32
#define MTOT   16384               // NB * HWSZ

// K ordering everywhere: k' = tap*256 + c (tap-major).

typedef __attribute__((ext_vector_type(4)))  float  floatx4;
typedef __attribute__((ext_vector_type(16))) float  floatx16;
typedef __attribute__((ext_vector_type(8)))  short  short8;
typedef __attribute__((ext_vector_type(4)))  short  short4v;
typedef __attribute__((ext_vector_type(4)))  int    intx4;

__device__ __forceinline__ unsigned short f2bf(float f) {
  union { float f; unsigned u; } v; v.f = f;
  unsigned r = v.u + 0x7FFF + ((v.u >> 16) & 1);   // round-to-nearest-even
  return (unsigned short)(r >> 16);
}
__device__ __forceinline__ float b2f(unsigned short s) {
  union { unsigned u; float f; } v; v.u = ((unsigned)s) << 16;
  return v.f;
}
// bf16 pair extraction from a packed u32 (2 bf16 in one dword)
__device__ __forceinline__ float lo16f(int u) {
  union { int i; float f; } v; v.i = u << 16; return v.f;
}
__device__ __forceinline__ float hi16f(int u) {
  union { int i; float f; } v; v.i = u & 0xFFFF0000; return v.f;
}
// HW packed f32->2xbf16 convert (RNE, same rounding as f2bf).
__device__ __forceinline__ unsigned cvt_pk_bf16(float lo, float hi) {
  unsigned r;
  asm("v_cvt_pk_bf16_f32 %0, %1, %2" : "=v"(r) : "v"(lo), "v"(hi));
  return r;
}

// Bilinear pack of 8 channels: 4 corner dword-quads -> 8 bf16 -> 16B LDS store.
__device__ __forceinline__ void pack8(const intx4& c0, const intx4& c1,
                                      const intx4& c2, const intx4& c3,
                                      const float4& w, unsigned short* dst) {
  intx4 o;
#pragma unroll
  for (int jj = 0; jj < 4; ++jj) {
    float v0 = w.x * lo16f(c0[jj]) + w.y * lo16f(c1[jj]) +
               w.z * lo16f(c2[jj]) + w.w * lo16f(c3[jj]);
    float v1 = w.x * hi16f(c0[jj]) + w.y * hi16f(c1[jj]) +
               w.z * hi16f(c2[jj]) + w.w * hi16f(c3[jj]);
    o[jj] = (int)cvt_pk_bf16(v0, v1);
  }
  *(intx4*)dst = o;
}

// LDS-only barrier: orders ds_write/ds_read across the workgroup WITHOUT
// draining vmcnt (global prefetch survives the barrier).
#define LDS_BARRIER() asm volatile("s_waitcnt lgkmcnt(0)\n\ts_barrier" ::: "memory")

// ---------------------------------------------------------------------------
// MAIN-PATH workspace (bytes):
//   Bfrag  : [144 s16][8 nt][64 lane][8 bf16]  = 1,179,648  (32x32x16 frag order)
//   B2frag : [72 s32][2 nt][64 lane][8 bf16]   =   147,456  (16x16x32 frag order)
//   xt     : [4][64][64][256] bf16             = 8,388,608  (channel-last x)
#define WSM_BFRAG   0
#define WSM_B2FRAG  1179648
#define WSM_XT      (1179648 + 147456)
#define WSM_END     (WSM_XT + NB * HWSZ * CIN * 2)
// FALLBACK workspace (round-2 path, only if ws is tiny):
#define WSF_BW      0
#define WSF_B2W     (KTOT * OUTC * 2)
#define WSF_OM      (WSF_B2W + KTOT * 32 * 2)
#define WSF_END     (WSF_OM + NB * 27 * HWSZ * 4)

// ---------------------------------------------------------------------------
// Kernel 0 (main): xpose (blocks 0..255) + Bfrag pack (256..543) + B2frag
// pack (544..579).  [REVERTED to R2 version: the R3 LDS-staged variant was
// ~9 us slower — frag pack concentrated on 72 CUs with serial ds_read_u16.]
// ---------------------------------------------------------------------------
__global__ __launch_bounds__(256) void prep_main_kernel(
    const float* __restrict__ dcn_w, const float* __restrict__ offw,
    const float* __restrict__ x,
    unsigned short* __restrict__ Bfrag, unsigned short* __restrict__ B2frag,
    unsigned short* __restrict__ xt) {
  int bid = blockIdx.x;
  int tid = threadIdx.x;
  if (bid < 256) {
    __shared__ unsigned short T[64 * 266];   // [w][c], pad 266
    int img = bid >> 6, h = bid & 63;
    const float* xp = x + (size_t)img * CIN * HWSZ + h * 64;
    int w = tid & 63, cq = tid >> 6;
    for (int cb = 0; cb < 256; cb += 4) {
      int c = cb + cq;
      T[w * 266 + c] = f2bf(xp[(size_t)c * HWSZ + w]);   // lanes=w: coalesced
    }
    __syncthreads();
    int w2 = tid >> 2, cg = (tid & 3) << 6;
    unsigned short* o = xt + ((size_t)(img * 64 + h) * 64 + w2) * 256 + cg;
#pragma unroll
    for (int i = 0; i < 64; i += 8) {
      short8 v = *(short8*)&T[w2 * 266 + cg + i];
      *(short8*)(o + i) = v;
    }
  } else if (bid < 544) {
    // Bfrag: e in [0, 73728): lane=e&63, nt=(e>>6)&7, s16=e>>9
    int e = (bid - 256) * 256 + tid;
    int lane = e & 63, nt = (e >> 6) & 7, s16 = e >> 9;
    int n = nt * 32 + (lane & 31);
    int kb = s16 * 16 + ((lane >> 5) << 3);
    short8 pk;
#pragma unroll
    for (int j = 0; j < 8; ++j) {
      int k = kb + j;
      pk[j] = (short)f2bf(dcn_w[n * KTOT + (k & 255) * 9 + (k >> 8)]);
    }
    *(short8*)(Bfrag + (size_t)e * 8) = pk;
  } else {
    // B2frag: e in [0, 9216): lane=e&63, nt=(e>>6)&1, s32=e>>7
    int e = (bid - 544) * 256 + tid;
    int lane = e & 63, nt = (e >> 6) & 1, s32 = e >> 7;
    int n = nt * 16 + (lane & 15);
    int kb = s32 * 32 + ((lane >> 4) << 3);
    short8 pk;
#pragma unroll
    for (int j = 0; j < 8; ++j) {
      int k = kb + j;
      pk[j] = (n < 27) ? (short)f2bf(offw[n * KTOT + (k & 255) * 9 + (k >> 8)])
                       : (short)0;
    }
    *(short8*)(B2frag + (size_t)e * 8) = pk;
  }
}

// ---------------------------------------------------------------------------
// Kernel 1 (main): FULLY FUSED offset-conv + sampling + GEMM, v9.
// v9: M-SPLIT for cross-block TLP. Block = half a row: (img, h, w-half),
// M=32, N=256, K=2304. Grid 512 (XCD-swizzled), 512 thr (8 waves),
// __launch_bounds__(512,2) -> 2 INDEPENDENT blocks/CU (4 waves/SIMD).
// R3 evidence: single block/CU with per-step barriers ran the three pipes
// (VMEM ~1150cy, VALU ~900cy, MFMA ~200cy per step) WORSE than serially
// (3287 cy/step) — latency bubbles had nothing to fill them. Co-resident
// independent blocks fill each other's barrier/latency stalls.
// Cost: Bfrag read per half-row (2x B L2 traffic) — L2 has headroom.
// Keeps: 4-buffer Ald rotation, LDS-only barrier per super-step, setprio,
// pack8 (cvt_pk), XCD swizzle (bid=(raw&7)*64+raw>>3: XCD k owns rows
// [k*32,(k+1)*32) both halves).
// Waves 0-3 produce A (sample+pack, 8ch/thread); all 8 waves load B + MFMA.
// ---------------------------------------------------------------------------
__global__ __launch_bounds__(512, 2) void dcn_fused_kernel(
    const unsigned short* __restrict__ xt,
    const unsigned short* __restrict__ Bfrag,
    const unsigned short* __restrict__ B2frag,
    const float* __restrict__ ob, float* __restrict__ out) {
  __shared__ unsigned short Ald[4][260 * 8];    // 16.6 KB: 4 bufs x 4 granules(65)
  __shared__ intx4  sOff[288];                  //  4.6 KB
  __shared__ float4 sWt[288];                   //  4.6 KB
  __shared__ float  omp[4 * 32 * 36];           // 18.4 KB conv partials

  int braw = blockIdx.x;                // 0..511
  int bid  = ((braw & 7) << 6) + (braw >> 3);   // XCD-contiguous
  int rowid = bid >> 1, half = bid & 1;
  int img = rowid >> 6, h = rowid & 63;
  int w0 = half << 5;                   // w-half base: 0 or 32
  const unsigned short* xb = xt + (size_t)img * HWSZ * 256;

  int tid  = threadIdx.x;
  int lane = tid & 63, q = tid >> 6;    // 8 waves
  int quad = lane >> 4, l15 = lane & 15;
  int l31  = lane & 31,  lh5 = lane >> 5;

  // ================= Phase A: offset conv (waves 0-3, K-split), M=32 ======
  if (q < 4) {
    floatx4 cacc[2][2];
#pragma unroll
    for (int mt = 0; mt < 2; ++mt)
#pragma unroll
      for (int nt = 0; nt < 2; ++nt) cacc[mt][nt] = (floatx4){0.f, 0.f, 0.f, 0.f};
    short8 cpa[2][2];
    short8 cpb[2][2];

#define CONV_LOAD(I, SLOT)                                                     \
  {                                                                            \
    int s = q + (I) * 4;                                                       \
    int t = s >> 3;                                                            \
    int dy = t / 3 - 1, dx = t % 3 - 1;                                        \
    int y = h + dy;                                                            \
    int cb0 = ((s & 7) << 5) + (quad << 3);                                    \
    _Pragma("unroll")                                                          \
    for (int mt = 0; mt < 2; ++mt) {                                           \
      int xx = w0 + mt * 16 + l15 + dx;                                        \
      short8 v = {0, 0, 0, 0, 0, 0, 0, 0};                                     \
      if (((unsigned)y < 64u) && ((unsigned)xx < 64u))                         \
        v = *(const short8*)(xb + ((y * 64 + xx) << 8) + cb0);                 \
      cpa[SLOT][mt] = v;                                                       \
    }                                                                          \
    _Pragma("unroll")                                                          \
    for (int nt = 0; nt < 2; ++nt)                                             \
      cpb[SLOT][nt] = *(const short8*)(B2frag + (((s * 2 + nt) * 64 + lane) << 3)); \
  }

    CONV_LOAD(0, 0);
#pragma unroll 2
    for (int i = 0; i < 18; ++i) {
      int sl = i & 1;
      if (i < 17) CONV_LOAD(i + 1, sl ^ 1);
#pragma unroll
      for (int mt = 0; mt < 2; ++mt)
#pragma unroll
        for (int nt = 0; nt < 2; ++nt)
          cacc[mt][nt] = __builtin_amdgcn_mfma_f32_16x16x32_bf16(
              cpa[sl][mt], cpb[sl][nt], cacc[mt][nt], 0, 0, 0);
    }
#undef CONV_LOAD
#pragma unroll
    for (int mt = 0; mt < 2; ++mt)
#pragma unroll
      for (int nt = 0; nt < 2; ++nt) {
        int oc = nt * 16 + l15;
        float4 vv = make_float4(cacc[mt][nt][0], cacc[mt][nt][1],
                                cacc[mt][nt][2], cacc[mt][nt][3]);
        *(float4*)&omp[(q * 32 + oc) * 36 + mt * 16 + quad * 4] = vv;
      }
  }
  __syncthreads();

  // ---- bilinear params: 9 taps x 32 w (sum 4 K-partials + bias) ----
  if (tid < 288) {
    int v = tid;
    int w = v & 31, t = v >> 5;         // w local to half
    int wg = w0 + w;
    int ky = t / 3, kx = t % 3;
    float offy = omp[(0 * 32 + 2 * t) * 36 + w] + omp[(1 * 32 + 2 * t) * 36 + w] +
                 omp[(2 * 32 + 2 * t) * 36 + w] + omp[(3 * 32 + 2 * t) * 36 + w] +
                 ob[2 * t];
    float offx = omp[(0 * 32 + 2 * t + 1) * 36 + w] + omp[(1 * 32 + 2 * t + 1) * 36 + w] +
                 omp[(2 * 32 + 2 * t + 1) * 36 + w] + omp[(3 * 32 + 2 * t + 1) * 36 + w] +
                 ob[2 * t + 1];
    float mraw = omp[(0 * 32 + 18 + t) * 36 + w] + omp[(1 * 32 + 18 + t) * 36 + w] +
                 omp[(2 * 32 + 18 + t) * 36 + w] + omp[(3 * 32 + 18 + t) * 36 + w] +
                 ob[18 + t];
    float mv   = 1.0f / (1.0f + __expf(-mraw));
    float him  = (float)(h - 1 + ky) + offy;
    float wim  = (float)(wg - 1 + kx) + offx;
    float y0f = floorf(him), x0f = floorf(wim);
    float lhf = him - y0f, lwf = wim - x0f;
    int y0 = (int)y0f, x0i = (int)x0f;
    bool vy0 = (y0 >= 0) && (y0 < HH);
    bool vy1 = (y0 + 1 >= 0) && (y0 + 1 < HH);
    bool vx0 = (x0i >= 0) && (x0i < WW);
    bool vx1 = (x0i + 1 >= 0) && (x0i + 1 < WW);
    float hh_ = 1.0f - lhf, hw_ = 1.0f - lwf;
    float4 wt;
    wt.x = (vy0 && vx0) ? hh_ * hw_ * mv : 0.0f;
    wt.y = (vy0 && vx1) ? hh_ * lwf * mv : 0.0f;
    wt.z = (vy1 && vx0) ? lhf * hw_ * mv : 0.0f;
    wt.w = (vy1 && vx1) ? lhf * lwf * mv : 0.0f;
    int y0c = min(max(y0, 0), 63), y1c = min(max(y0 + 1, 0), 63);
    int x0c = min(max(x0i, 0), 63), x1c = min(max(x0i + 1, 0), 63);
    intx4 ii = {(y0c * 64 + x0c) << 8, (y0c * 64 + x1c) << 8,
                (y1c * 64 + x0c) << 8, (y1c * 64 + x1c) << 8};
    sOff[v] = ii;
    sWt[v]  = wt;
  }

  // ================= Phase B: fused sampling + GEMM ========================
  floatx16 acc;
#pragma unroll
  for (int e = 0; e < 16; ++e) acc[e] = 0.f;

  // producers: waves 0-3 (tid<256). sm = row (0..31), chk = 8-ch chunk (0..7)
  int sm  = (tid >> 3) & 31;
  int chk = tid & 7;
  // write granule: g = sub (=chk>>1), row = (chk&1)*32 + sm
  int wgran = (chk >> 1) * 65 + ((chk & 1) << 5) + sm;
  bool producer = (tid < 256);

  short8 bfr[2][4];            // B frags [step parity][sub]
  intx4  cr[2][4];             // corner regs, slot = (target step) & 1
  float4 pwt[2];               // weights matching cr slots

  __syncthreads();             // params ready

  // ---- prologue: pack steps 0,1; prefetch corners 2,3; B 0,1 ----
#pragma unroll
  for (int sub = 0; sub < 4; ++sub) {
    bfr[0][sub] = *(const short8*)(
        Bfrag + (((size_t)(0 + sub) * 8 + q) * 64 + lane) * 8);
    bfr[1][sub] = *(const short8*)(
        Bfrag + (((size_t)(4 + sub) * 8 + q) * 64 + lane) * 8);
  }
  if (producer) {
    intx4 off = sOff[sm];
    float4 wgt = sWt[sm];
    {
      int cb = chk * 8;                      // s=0
      intx4 c0 = *(const intx4*)(xb + off.x + cb);
      intx4 c1 = *(const intx4*)(xb + off.y + cb);
      intx4 c2 = *(const intx4*)(xb + off.z + cb);
      intx4 c3 = *(const intx4*)(xb + off.w + cb);
      pack8(c0, c1, c2, c3, wgt, &Ald[0][wgran * 8]);
    }
    {
      int cb = 64 + chk * 8;                 // s=1
      intx4 c0 = *(const intx4*)(xb + off.x + cb);
      intx4 c1 = *(const intx4*)(xb + off.y + cb);
      intx4 c2 = *(const intx4*)(xb + off.z + cb);
      intx4 c3 = *(const intx4*)(xb + off.w + cb);
      pack8(c0, c1, c2, c3, wgt, &Ald[1][wgran * 8]);
    }
    {
      int cb = 128 + chk * 8;                // s=2 -> cr[0]
      pwt[0] = wgt;
      cr[0][0] = *(const intx4*)(xb + off.x + cb);
      cr[0][1] = *(const intx4*)(xb + off.y + cb);
      cr[0][2] = *(const intx4*)(xb + off.z + cb);
      cr[0][3] = *(const intx4*)(xb + off.w + cb);
    }
    {
      int cb = 192 + chk * 8;                // s=3 -> cr[1]
      pwt[1] = wgt;
      cr[1][0] = *(const intx4*)(xb + off.x + cb);
      cr[1][1] = *(const intx4*)(xb + off.y + cb);
      cr[1][2] = *(const intx4*)(xb + off.z + cb);
      cr[1][3] = *(const intx4*)(xb + off.w + cb);
    }
  }
  LDS_BARRIER();   // Ald[0..1] visible; corner/B prefetch stays in flight

  // ---- main loop: 18 super-steps x 2 K64-steps ----
  // Invariants at super-step S (s0=2S): Ald[s0&3],Ald[s1&3] packed;
  // cr[0]=corners(s0+2), cr[1]=corners(s0+3); bfr[0]=B(s0), bfr[1]=B(s1).
#pragma unroll 2
  for (int S = 0; S < 18; ++S) {
    int s0 = 2 * S, s1 = s0 + 1;
    // ---- half 0: MFMA(s0) ----
    __builtin_amdgcn_s_setprio(1);
#pragma unroll
    for (int sub = 0; sub < 4; ++sub) {
      short8 a = *(short8*)&Ald[s0 & 3][(sub * 65 + lane) * 8];
      acc = __builtin_amdgcn_mfma_f32_32x32x16_bf16(a, bfr[0][sub], acc, 0, 0, 0);
    }
    __builtin_amdgcn_s_setprio(0);
    if (s0 + 2 < 36) {
      int s16b = (s0 + 2) * 4;
#pragma unroll
      for (int sub = 0; sub < 4; ++sub)
        bfr[0][sub] = *(const short8*)(
            Bfrag + (((size_t)(s16b + sub) * 8 + q) * 64 + lane) * 8);
      if (producer)
        pack8(cr[0][0], cr[0][1], cr[0][2], cr[0][3], pwt[0],
              &Ald[(s0 + 2) & 3][wgran * 8]);
    }
    if (producer && (s0 + 4 < 36)) {
      int s4 = s0 + 4, t4 = s4 >> 2;
      intx4 off = sOff[t4 * 32 + sm];
      pwt[0] = sWt[t4 * 32 + sm];
      int cb = (s4 & 3) * 64 + chk * 8;
      cr[0][0] = *(const intx4*)(xb + off.x + cb);
      cr[0][1] = *(const intx4*)(xb + off.y + cb);
      cr[0][2] = *(const intx4*)(xb + off.z + cb);
      cr[0][3] = *(const intx4*)(xb + off.w + cb);
    }
    // ---- half 1: MFMA(s1) ----
    __builtin_amdgcn_s_setprio(1);
#pragma unroll
    for (int sub = 0; sub < 4; ++sub) {
      short8 a = *(short8*)&Ald[s1 & 3][(sub * 65 + lane) * 8];
      acc = __builtin_amdgcn_mfma_f32_32x32x16_bf16(a, bfr[1][sub], acc, 0, 0, 0);
    }
    __builtin_amdgcn_s_setprio(0);
    if (s1 + 2 < 36) {
      int s16b = (s1 + 2) * 4;
#pragma unroll
      for (int sub = 0; sub < 4; ++sub)
        bfr[1][sub] = *(const short8*)(
            Bfrag + (((size_t)(s16b + sub) * 8 + q) * 64 + lane) * 8);
      if (producer)
        pack8(cr[1][0], cr[1][1], cr[1][2], cr[1][3], pwt[1],
              &Ald[(s1 + 2) & 3][wgran * 8]);
    }
    if (producer && (s1 + 4 < 36)) {
      int s4 = s1 + 4, t4 = s4 >> 2;
      intx4 off = sOff[t4 * 32 + sm];
      pwt[1] = sWt[t4 * 32 + sm];
      int cb = (s4 & 3) * 64 + chk * 8;
      cr[1][0] = *(const intx4*)(xb + off.x + cb);
      cr[1][1] = *(const intx4*)(xb + off.y + cb);
      cr[1][2] = *(const intx4*)(xb + off.z + cb);
      cr[1][3] = *(const intx4*)(xb + off.w + cb);
    }
    // ONE barrier per super-step: reads {s0,s1}, writes {s0+2,s0+3} — all 4
    // buffers distinct mod 4 -> no intra-super-step hazards.
    LDS_BARRIER();
  }

  // ---- epilogue: D col = oc (lane&31), row = (r&3)+8*(r>>2)+4*(lane>>5) ----
  int oc = q * 32 + l31;
  float* obase = out + (((size_t)img * OUTC + oc) << 12) + h * 64 + w0 + lh5 * 4;
#pragma unroll
  for (int rg = 0; rg < 4; ++rg) {
    float4 vv = make_float4(acc[rg * 4 + 0], acc[rg * 4 + 1],
                            acc[rg * 4 + 2], acc[rg * 4 + 3]);
    *(float4*)(obase + rg * 8) = vv;
  }
}

// ===========================================================================
// FALLBACK PATH (round-2 kernels) — only if ws is too small (< ~9.7 MB).
// ===========================================================================
__global__ __launch_bounds__(256) void prep_fb_kernel(
    const float* __restrict__ dcn_w, const float* __restrict__ offw,
    unsigned short* __restrict__ Bw, unsigned short* __restrict__ B2w) {
  int oc = blockIdx.x;
  for (int k = threadIdx.x; k < KTOT; k += 256) {
    int t = k >> 8, c = k & 255;
    Bw[oc * KTOT + k] = f2bf(dcn_w[oc * KTOT + c * 9 + t]);
    if (oc < 32)
      B2w[oc * KTOT + k] = (oc < 27) ? f2bf(offw[oc * KTOT + c * 9 + t])
                                     : (unsigned short)0;
  }
}

__global__ __launch_bounds__(256) void conv_offset_kernel(
    const float* __restrict__ x, const unsigned short* __restrict__ B2w,
    const float* __restrict__ ob, float* __restrict__ om) {
  __shared__ unsigned short A_lds[64 * 40];
  __shared__ unsigned short B_lds[32 * 40];
  int bid = blockIdx.x;
  int n = bid >> 6, h = bid & 63;
  int tid = threadIdx.x, lane = tid & 63, q = tid >> 6;
  const float* xn = x + n * (CIN * HWSZ);
  floatx4 acc0 = {0.f, 0.f, 0.f, 0.f}, acc1 = {0.f, 0.f, 0.f, 0.f};
  int w = tid & 63, cg = tid >> 6, ocb = tid >> 3, part = tid & 7;
  for (int s = 0; s < NSTEPS; ++s) {
    int t = s >> 3, c0 = (s & 7) << 5;
    int dy = t / 3 - 1, dx = t % 3 - 1;
    __syncthreads();
    {
      int y = h + dy, xx = w + dx;
      bool inb = ((unsigned)y < 64u) && ((unsigned)xx < 64u);
      const float* xb = xn + (c0 + cg * 8) * HWSZ + y * 64 + xx;
      short8 pk;
#pragma unroll
      for (int j = 0; j < 8; ++j) { float v = inb ? xb[j * HWSZ] : 0.0f; pk[j] = (short)f2bf(v); }
      *(short8*)&A_lds[w * 40 + cg * 8] = pk;
    }
    { const unsigned short* bp = B2w + ocb * KTOT + (t << 8) + c0 + part * 4;
      *(short4v*)&B_lds[ocb * 40 + part * 4] = *(const short4v*)bp; }
    __syncthreads();
    int fr = (lane >> 4) * 8;
    short8 af  = *(short8*)&A_lds[(q * 16 + (lane & 15)) * 40 + fr];
    short8 bf0 = *(short8*)&B_lds[((lane & 15)) * 40 + fr];
    short8 bf1 = *(short8*)&B_lds[(16 + (lane & 15)) * 40 + fr];
    acc0 = __builtin_amdgcn_mfma_f32_16x16x32_bf16(af, bf0, acc0, 0, 0, 0);
    acc1 = __builtin_amdgcn_mfma_f32_16x16x32_bf16(af, bf1, acc1, 0, 0, 0);
  }
  int g = lane >> 4;
#pragma unroll
  for (int nt = 0; nt < 2; ++nt) {
    floatx4 a = nt ? acc1 : acc0;
    int oc = nt * 16 + (lane & 15);
    if (oc < 27) {
      float bias = ob[oc];
#pragma unroll
      for (int r = 0; r < 4; ++r) {
        int wm = q * 16 + g * 4 + r;
        float val = a[r] + bias;
        if (oc >= 18) val = 1.0f / (1.0f + __expf(-val));
        om[((n * 27 + oc) << 12) + h * 64 + wm] = val;
      }
    }
  }
}

__global__ __launch_bounds__(256) void dcn_main_kernel(
    const float* __restrict__ x, const float* __restrict__ om,
    const unsigned short* __restrict__ Bw, float* __restrict__ out) {
  __shared__ unsigned short A_lds[32 * 40];
  __shared__ unsigned short B_lds[256 * 40];
  __shared__ int    sY[288];
  __shared__ int    sX[288];
  __shared__ float4 sW[288];
  int bid = blockIdx.x;
  int n = bid >> 7, rem = bid & 127, h = rem >> 1, w0 = (rem & 1) << 5;
  int tid = threadIdx.x, lane = tid & 63, q = tid >> 6;
  const float* xn  = x + n * (CIN * HWSZ);
  const float* omn = om + n * (27 * HWSZ);
  for (int v = tid; v < 288; v += 256) {
    int m = v & 31, t = v >> 5;
    int ky = t / 3, kx = t % 3;
    int wg = w0 + m, sp = h * 64 + wg;
    float offy = omn[(2 * t) * HWSZ + sp];
    float offx = omn[(2 * t + 1) * HWSZ + sp];
    float mv   = omn[(18 + t) * HWSZ + sp];
    float him = (float)(h - 1 + ky) + offy;
    float wim = (float)(wg - 1 + kx) + offx;
    float y0f = floorf(him), x0f = floorf(wim);
    float lh = him - y0f, lw = wim - x0f;
    int y0 = (int)y0f, x0i = (int)x0f;
    bool vy0 = (y0 >= 0) && (y0 < HH), vy1 = (y0 + 1 >= 0) && (y0 + 1 < HH);
    bool vx0 = (x0i >= 0) && (x0i < WW), vx1 = (x0i + 1 >= 0) && (x0i + 1 < WW);
    float hh_ = 1.0f - lh, hw_ = 1.0f - lw;
    float4 wt;
    wt.x = (vy0 && vx0) ? hh_ * hw_ * mv : 0.0f;
    wt.y = (vy0 && vx1) ? hh_ * lw  * mv : 0.0f;
    wt.z = (vy1 && vx0) ? lh  * hw_ * mv : 0.0f;
    wt.w = (vy1 && vx1) ? lh  * lw  * mv : 0.0f;
    sY[v] = y0; sX[v] = x0i; sW[v] = wt;
  }
  floatx4 acc[2][4];
#pragma unroll
  for (int mi = 0; mi < 2; ++mi)
#pragma unroll
    for (int nj = 0; nj < 4; ++nj) acc[mi][nj] = (floatx4){0.f, 0.f, 0.f, 0.f};
  int m = tid & 31, cg = tid >> 5, n0 = q * 64;
  for (int s = 0; s < NSTEPS; ++s) {
    int t = s >> 3, c0 = (s & 7) << 5;
    __syncthreads();
    {
      int p = t * 32 + m;
      int y0 = sY[p], x0i = sX[p];
      float4 wt = sW[p];
      int y0c = min(max(y0, 0), 63), y1c = min(max(y0 + 1, 0), 63);
      int x0c = min(max(x0i, 0), 63), x1c = min(max(x0i + 1, 0), 63);
      int i00 = y0c * 64 + x0c, i01 = y0c * 64 + x1c;
      int i10 = y1c * 64 + x0c, i11 = y1c * 64 + x1c;
      const float* xb = xn + (c0 + cg * 4) * HWSZ;
      short4v pk;
#pragma unroll
      for (int j = 0; j < 4; ++j) {
        const float* xc = xb + j * HWSZ;
        float v = wt.x * xc[i00] + wt.y * xc[i01] + wt.z * xc[i10] + wt.w * xc[i11];
        pk[j] = (short)f2bf(v);
      }
      *(short4v*)&A_lds[m * 40 + cg * 4] = pk;
    }
    {
      const short8* bp = (const short8*)(Bw + tid * KTOT + (t << 8) + c0);
      short8 b0 = bp[0], b1 = bp[1], b2 = bp[2], b3 = bp[3];
      short8* dst = (short8*)&B_lds[tid * 40];
      dst[0] = b0; dst[1] = b1; dst[2] = b2; dst[3] = b3;
    }
    __syncthreads();
    int fr = (lane >> 4) * 8;
    short8 a0 = *(short8*)&A_lds[((lane & 15)) * 40 + fr];
    short8 a1 = *(short8*)&A_lds[(16 + (lane & 15)) * 40 + fr];
#pragma unroll
    for (int nj = 0; nj < 4; ++nj) {
      short8 bfp = *(short8*)&B_lds[(n0 + nj * 16 + (lane & 15)) * 40 + fr];
      acc[0][nj] = __builtin_amdgcn_mfma_f32_16x16x32_bf16(a0, bfp, acc[0][nj], 0, 0, 0);
      acc[1][nj] = __builtin_amdgcn_mfma_f32_16x16x32_bf16(a1, bfp, acc[1][nj], 0, 0, 0);
    }
  }
  int g = lane >> 4;
#pragma unroll
  for (int mi = 0; mi < 2; ++mi) {
    int wm = w0 + mi * 16 + g * 4;
#pragma unroll
    for (int nj = 0; nj < 4; ++nj) {
      int oc = n0 + nj * 16 + (lane & 15);
      float4 vv = make_float4(acc[mi][nj][0], acc[mi][nj][1],
                              acc[mi][nj][2], acc[mi][nj][3]);
      *(float4*)&out[((n * OUTC + oc) << 12) + h * 64 + wm] = vv;
    }
  }
}

// ---------------------------------------------------------------------------
extern "C" void kernel_launch(void* const* d_in, const int* in_sizes, int n_in,
                              void* d_out, int out_size, void* d_ws, size_t ws_size,
                              hipStream_t stream) {
  const float* x     = (const float*)d_in[0];
  const float* offw  = (const float*)d_in[1];
  const float* ob    = (const float*)d_in[2];
  const float* dcn_w = (const float*)d_in[3];
  float* out = (float*)d_out;

  if (ws_size >= (size_t)WSM_END) {
    unsigned short* Bfrag  = (unsigned short*)((char*)d_ws + WSM_BFRAG);
    unsigned short* B2frag = (unsigned short*)((char*)d_ws + WSM_B2FRAG);
    unsigned short* xtb    = (unsigned short*)((char*)d_ws + WSM_XT);
    // main path: 2 launches total
    prep_main_kernel<<<580, 256, 0, stream>>>(dcn_w, offw, x, Bfrag, B2frag, xtb);
    dcn_fused_kernel<<<512, 512, 0, stream>>>(xtb, Bfrag, B2frag, ob, out);
  } else {
    unsigned short* Bw  = (unsigned short*)((char*)d_ws + WSF_BW);
    unsigned short* B2w = (unsigned short*)((char*)d_ws + WSF_B2W);
    float*          omb = (float*)((char*)d_ws + WSF_OM);
    prep_fb_kernel<<<256, 256, 0, stream>>>(dcn_w, offw, Bw, B2w);
    conv_offset_kernel<<<NB * HH, 256, 0, stream>>>(x, B2w, ob, omb);
    dcn_main_kernel<<<NB * HH * 2, 256, 0, stream>>>(x, omb, Bw, out);
  }
}

// Round 5
// 123.414 us; speedup vs baseline: 1.0838x; 1.0838x over previous
//
#include <hip/hip_runtime.h>
#include <hip/hip_bf16.h>
#include <math.h>

// Problem constants (N, C, H, W) = (4, 256, 64, 64), out_C = 256, FS=3, pad=1, stride=1
#define NB     4
#define CIN    256
#define HH     64
#define WW     64
#define OUTC   256
#define K2     9
#define KTOT   2304                // CIN * K2
#define HWSZ   4096                // HH * WW
#define NSTEPS 72                  // KTOT / 32
#define MTOT   16384               // NB * HWSZ

// K ordering everywhere: k' = tap*256 + c (tap-major).

typedef __attribute__((ext_vector_type(4)))  float  floatx4;
typedef __attribute__((ext_vector_type(16))) float  floatx16;
typedef __attribute__((ext_vector_type(8)))  short  short8;
typedef __attribute__((ext_vector_type(4)))  short  short4v;
typedef __attribute__((ext_vector_type(4)))  int    intx4;

__device__ __forceinline__ unsigned short f2bf(float f) {
  union { float f; unsigned u; } v; v.f = f;
  unsigned r = v.u + 0x7FFF + ((v.u >> 16) & 1);   // round-to-nearest-even
  return (unsigned short)(r >> 16);
}
__device__ __forceinline__ float b2f(unsigned short s) {
  union { unsigned u; float f; } v; v.u = ((unsigned)s) << 16;
  return v.f;
}
// bf16 pair extraction from a packed u32 (2 bf16 in one dword)
__device__ __forceinline__ float lo16f(int u) {
  union { int i; float f; } v; v.i = u << 16; return v.f;
}
__device__ __forceinline__ float hi16f(int u) {
  union { int i; float f; } v; v.i = u & 0xFFFF0000; return v.f;
}
// HW packed f32->2xbf16 convert (RNE, same rounding as f2bf).
__device__ __forceinline__ unsigned cvt_pk_bf16(float lo, float hi) {
  unsigned r;
  asm("v_cvt_pk_bf16_f32 %0, %1, %2" : "=v"(r) : "v"(lo), "v"(hi));
  return r;
}

// Bilinear pack of 8 channels: 4 corner dword-quads -> 8 bf16 -> 16B LDS store.
__device__ __forceinline__ void pack8(const intx4& c0, const intx4& c1,
                                      const intx4& c2, const intx4& c3,
                                      const float4& w, unsigned short* dst) {
  intx4 o;
#pragma unroll
  for (int jj = 0; jj < 4; ++jj) {
    float v0 = w.x * lo16f(c0[jj]) + w.y * lo16f(c1[jj]) +
               w.z * lo16f(c2[jj]) + w.w * lo16f(c3[jj]);
    float v1 = w.x * hi16f(c0[jj]) + w.y * hi16f(c1[jj]) +
               w.z * hi16f(c2[jj]) + w.w * hi16f(c3[jj]);
    o[jj] = (int)cvt_pk_bf16(v0, v1);
  }
  *(intx4*)dst = o;
}

// LDS-only barrier: orders ds_write/ds_read across the workgroup WITHOUT
// draining vmcnt (global prefetch survives the barrier).
#define LDS_BARRIER() asm volatile("s_waitcnt lgkmcnt(0)\n\ts_barrier" ::: "memory")

// ---------------------------------------------------------------------------
// MAIN-PATH workspace (bytes):
//   Bfrag  : [144 s16][8 nt][64 lane][8 bf16]  = 1,179,648  (32x32x16 frag order)
//   B2frag : [72 s32][2 nt][64 lane][8 bf16]   =   147,456  (16x16x32 frag order)
//   xt     : [4][64][64][256] bf16             = 8,388,608  (channel-last x)
#define WSM_BFRAG   0
#define WSM_B2FRAG  1179648
#define WSM_XT      (1179648 + 147456)
#define WSM_END     (WSM_XT + NB * HWSZ * CIN * 2)
// FALLBACK workspace (round-2 path, only if ws is tiny):
#define WSF_BW      0
#define WSF_B2W     (KTOT * OUTC * 2)
#define WSF_OM      (WSF_B2W + KTOT * 32 * 2)
#define WSF_END     (WSF_OM + NB * 27 * HWSZ * 4)

// ---------------------------------------------------------------------------
// Kernel 0 (main): xpose (blocks 0..255) + Bfrag pack (256..543) + B2frag
// pack (544..579).  [R2 version — best measured prep]
// ---------------------------------------------------------------------------
__global__ __launch_bounds__(256) void prep_main_kernel(
    const float* __restrict__ dcn_w, const float* __restrict__ offw,
    const float* __restrict__ x,
    unsigned short* __restrict__ Bfrag, unsigned short* __restrict__ B2frag,
    unsigned short* __restrict__ xt) {
  int bid = blockIdx.x;
  int tid = threadIdx.x;
  if (bid < 256) {
    __shared__ unsigned short T[64 * 266];   // [w][c], pad 266
    int img = bid >> 6, h = bid & 63;
    const float* xp = x + (size_t)img * CIN * HWSZ + h * 64;
    int w = tid & 63, cq = tid >> 6;
    for (int cb = 0; cb < 256; cb += 4) {
      int c = cb + cq;
      T[w * 266 + c] = f2bf(xp[(size_t)c * HWSZ + w]);   // lanes=w: coalesced
    }
    __syncthreads();
    int w2 = tid >> 2, cg = (tid & 3) << 6;
    unsigned short* o = xt + ((size_t)(img * 64 + h) * 64 + w2) * 256 + cg;
#pragma unroll
    for (int i = 0; i < 64; i += 8) {
      short8 v = *(short8*)&T[w2 * 266 + cg + i];
      *(short8*)(o + i) = v;
    }
  } else if (bid < 544) {
    // Bfrag: e in [0, 73728): lane=e&63, nt=(e>>6)&7, s16=e>>9
    int e = (bid - 256) * 256 + tid;
    int lane = e & 63, nt = (e >> 6) & 7, s16 = e >> 9;
    int n = nt * 32 + (lane & 31);
    int kb = s16 * 16 + ((lane >> 5) << 3);
    short8 pk;
#pragma unroll
    for (int j = 0; j < 8; ++j) {
      int k = kb + j;
      pk[j] = (short)f2bf(dcn_w[n * KTOT + (k & 255) * 9 + (k >> 8)]);
    }
    *(short8*)(Bfrag + (size_t)e * 8) = pk;
  } else {
    // B2frag: e in [0, 9216): lane=e&63, nt=(e>>6)&1, s32=e>>7
    int e = (bid - 544) * 256 + tid;
    int lane = e & 63, nt = (e >> 6) & 1, s32 = e >> 7;
    int n = nt * 16 + (lane & 15);
    int kb = s32 * 32 + ((lane >> 4) << 3);
    short8 pk;
#pragma unroll
    for (int j = 0; j < 8; ++j) {
      int k = kb + j;
      pk[j] = (n < 27) ? (short)f2bf(offw[n * KTOT + (k & 255) * 9 + (k >> 8)])
                       : (short)0;
    }
    *(short8*)(B2frag + (size_t)e * 8) = pk;
  }
}

// ---------------------------------------------------------------------------
// Kernel 1 (main): FULLY FUSED offset-conv + sampling + GEMM, v10.
// Geometry = v8 (best measured): block = one (img,h) row, M=64, N=256,
// K=2304, grid 256 XCD-swizzled, 512 thr (8 waves, 2/SIMD).
// v10: ROLE-SKEWED SUPER-STEPS. v8's stall: all 8 waves run the identical
// phase sequence between barriers, so both waves on a SIMD are in the same
// phase simultaneously -> VMEM/VALU/MFMA pipes serialize in wall-clock
// (R4's cross-block attempt regressed: 2x B traffic + 2x Phase-A).
// Fix: waves 0-3 do {pack, corner-loads} THEN {MFMA, B-loads}; waves 4-7
// the reverse. SIMD i hosts waves q=i and q=i+4 (opposite roles) -> one
// wave feeds VALU while the other feeds MFMA/LDS. Same totals, same
// traffic, same single barrier per super-step; deps hold (MFMA(s) before
// bfr overwrite; pack(s+2) before cr overwrite; 4-buffer rotation keeps
// LDS hazard-free across the skew).
// ---------------------------------------------------------------------------
__global__ __launch_bounds__(512, 2) void dcn_fused_kernel(
    const unsigned short* __restrict__ xt,
    const unsigned short* __restrict__ Bfrag,
    const unsigned short* __restrict__ B2frag,
    const float* __restrict__ ob, float* __restrict__ out) {
  __shared__ unsigned short Ald[4][520 * 8];    // 16.6 KB 4-buffer rotation
  __shared__ intx4  sOff[576];                  //  9 KB
  __shared__ float4 sWt[576];                   //  9 KB
  __shared__ float  omp[4 * 32 * 68];           // 34.8 KB conv partials

  int braw = blockIdx.x;                // 0..255
  // XCD swizzle: XCD k (= braw%8) processes rows [k*32, (k+1)*32).
  int bid  = ((braw & 7) << 5) + (braw >> 3);
  int img = bid >> 6, h = bid & 63;
  const unsigned short* xb = xt + (size_t)img * HWSZ * 256;

  int tid  = threadIdx.x;
  int lane = tid & 63, q = tid >> 6;    // 8 waves
  int quad = lane >> 4, l15 = lane & 15;
  int l31  = lane & 31,  lh5 = lane >> 5;

  // ================= Phase A: offset conv (waves 0-3, K-split) =============
  if (q < 4) {
    floatx4 cacc[4][2];
#pragma unroll
    for (int mt = 0; mt < 4; ++mt)
#pragma unroll
      for (int nt = 0; nt < 2; ++nt) cacc[mt][nt] = (floatx4){0.f, 0.f, 0.f, 0.f};
    short8 cpa[2][4];
    short8 cpb[2][2];

#define CONV_LOAD(I, SLOT)                                                     \
  {                                                                            \
    int s = q + (I) * 4;                                                       \
    int t = s >> 3;                                                            \
    int dy = t / 3 - 1, dx = t % 3 - 1;                                        \
    int y = h + dy;                                                            \
    int cb0 = ((s & 7) << 5) + (quad << 3);                                    \
    _Pragma("unroll")                                                          \
    for (int mt = 0; mt < 4; ++mt) {                                           \
      int xx = mt * 16 + l15 + dx;                                             \
      short8 v = {0, 0, 0, 0, 0, 0, 0, 0};                                     \
      if (((unsigned)y < 64u) && ((unsigned)xx < 64u))                         \
        v = *(const short8*)(xb + ((y * 64 + xx) << 8) + cb0);                 \
      cpa[SLOT][mt] = v;                                                       \
    }                                                                          \
    _Pragma("unroll")                                                          \
    for (int nt = 0; nt < 2; ++nt)                                             \
      cpb[SLOT][nt] = *(const short8*)(B2frag + (((s * 2 + nt) * 64 + lane) << 3)); \
  }

    CONV_LOAD(0, 0);
#pragma unroll 2
    for (int i = 0; i < 18; ++i) {
      int sl = i & 1;
      if (i < 17) CONV_LOAD(i + 1, sl ^ 1);
#pragma unroll
      for (int mt = 0; mt < 4; ++mt)
#pragma unroll
        for (int nt = 0; nt < 2; ++nt)
          cacc[mt][nt] = __builtin_amdgcn_mfma_f32_16x16x32_bf16(
              cpa[sl][mt], cpb[sl][nt], cacc[mt][nt], 0, 0, 0);
    }
#undef CONV_LOAD
#pragma unroll
    for (int mt = 0; mt < 4; ++mt)
#pragma unroll
      for (int nt = 0; nt < 2; ++nt) {
        int oc = nt * 16 + l15;
        float4 vv = make_float4(cacc[mt][nt][0], cacc[mt][nt][1],
                                cacc[mt][nt][2], cacc[mt][nt][3]);
        *(float4*)&omp[(q * 32 + oc) * 68 + mt * 16 + quad * 4] = vv;
      }
  }
  __syncthreads();

  // ---- bilinear params: 9 taps x 64 w (sum 4 K-partials + bias) ----
  for (int v = tid; v < 576; v += 512) {
    int w = v & 63, t = v >> 6;
    int ky = t / 3, kx = t % 3;
    float offy = omp[(0 * 32 + 2 * t) * 68 + w] + omp[(1 * 32 + 2 * t) * 68 + w] +
                 omp[(2 * 32 + 2 * t) * 68 + w] + omp[(3 * 32 + 2 * t) * 68 + w] +
                 ob[2 * t];
    float offx = omp[(0 * 32 + 2 * t + 1) * 68 + w] + omp[(1 * 32 + 2 * t + 1) * 68 + w] +
                 omp[(2 * 32 + 2 * t + 1) * 68 + w] + omp[(3 * 32 + 2 * t + 1) * 68 + w] +
                 ob[2 * t + 1];
    float mraw = omp[(0 * 32 + 18 + t) * 68 + w] + omp[(1 * 32 + 18 + t) * 68 + w] +
                 omp[(2 * 32 + 18 + t) * 68 + w] + omp[(3 * 32 + 18 + t) * 68 + w] +
                 ob[18 + t];
    float mv   = 1.0f / (1.0f + __expf(-mraw));
    float him  = (float)(h - 1 + ky) + offy;
    float wim  = (float)(w - 1 + kx) + offx;
    float y0f = floorf(him), x0f = floorf(wim);
    float lhf = him - y0f, lwf = wim - x0f;
    int y0 = (int)y0f, x0i = (int)x0f;
    bool vy0 = (y0 >= 0) && (y0 < HH);
    bool vy1 = (y0 + 1 >= 0) && (y0 + 1 < HH);
    bool vx0 = (x0i >= 0) && (x0i < WW);
    bool vx1 = (x0i + 1 >= 0) && (x0i + 1 < WW);
    float hh_ = 1.0f - lhf, hw_ = 1.0f - lwf;
    float4 wt;
    wt.x = (vy0 && vx0) ? hh_ * hw_ * mv : 0.0f;
    wt.y = (vy0 && vx1) ? hh_ * lwf * mv : 0.0f;
    wt.z = (vy1 && vx0) ? lhf * hw_ * mv : 0.0f;
    wt.w = (vy1 && vx1) ? lhf * lwf * mv : 0.0f;
    int y0c = min(max(y0, 0), 63), y1c = min(max(y0 + 1, 0), 63);
    int x0c = min(max(x0i, 0), 63), x1c = min(max(x0i + 1, 0), 63);
    intx4 ii = {(y0c * 64 + x0c) << 8, (y0c * 64 + x1c) << 8,
                (y1c * 64 + x0c) << 8, (y1c * 64 + x1c) << 8};
    sOff[v] = ii;
    sWt[v]  = wt;
  }

  // ================= Phase B: fused sampling + GEMM ========================
  floatx16 acc[2];
#pragma unroll
  for (int mt = 0; mt < 2; ++mt)
#pragma unroll
    for (int e = 0; e < 16; ++e) acc[mt][e] = 0.f;

  int sm  = tid >> 3;          // sampler m row (0..63)
  int chk = tid & 7;           // 8-c chunk within K64 window
  // write granule: blk = sub*2 + mt, row = (chk&1)*32 + (m&31)
  int wgran = (((chk >> 1) << 1) + (sm >> 5)) * 65 + ((chk & 1) << 5) + (sm & 31);

  short8 bfr[2][4];            // B frags [step parity][sub]
  intx4  cr[2][4];             // corner regs, slot = (target step) & 1
  float4 pwt[2];               // weights matching cr slots

  __syncthreads();             // params ready

  // ---- prologue: pack steps 0,1; prefetch corners 2,3; B 0,1 ----
#pragma unroll
  for (int sub = 0; sub < 4; ++sub) {
    bfr[0][sub] = *(const short8*)(
        Bfrag + (((size_t)(0 + sub) * 8 + q) * 64 + lane) * 8);
    bfr[1][sub] = *(const short8*)(
        Bfrag + (((size_t)(4 + sub) * 8 + q) * 64 + lane) * 8);
  }
  {
    intx4 off = sOff[sm];
    float4 w0 = sWt[sm];
    {
      int cb = chk * 8;                      // s=0
      intx4 c0 = *(const intx4*)(xb + off.x + cb);
      intx4 c1 = *(const intx4*)(xb + off.y + cb);
      intx4 c2 = *(const intx4*)(xb + off.z + cb);
      intx4 c3 = *(const intx4*)(xb + off.w + cb);
      pack8(c0, c1, c2, c3, w0, &Ald[0][wgran * 8]);
    }
    {
      int cb = 64 + chk * 8;                 // s=1
      intx4 c0 = *(const intx4*)(xb + off.x + cb);
      intx4 c1 = *(const intx4*)(xb + off.y + cb);
      intx4 c2 = *(const intx4*)(xb + off.z + cb);
      intx4 c3 = *(const intx4*)(xb + off.w + cb);
      pack8(c0, c1, c2, c3, w0, &Ald[1][wgran * 8]);
    }
    {
      int cb = 128 + chk * 8;                // s=2 -> cr[0]
      pwt[0] = w0;
      cr[0][0] = *(const intx4*)(xb + off.x + cb);
      cr[0][1] = *(const intx4*)(xb + off.y + cb);
      cr[0][2] = *(const intx4*)(xb + off.z + cb);
      cr[0][3] = *(const intx4*)(xb + off.w + cb);
    }
    {
      int cb = 192 + chk * 8;                // s=3 -> cr[1]
      pwt[1] = w0;
      cr[1][0] = *(const intx4*)(xb + off.x + cb);
      cr[1][1] = *(const intx4*)(xb + off.y + cb);
      cr[1][2] = *(const intx4*)(xb + off.z + cb);
      cr[1][3] = *(const intx4*)(xb + off.w + cb);
    }
  }
  LDS_BARRIER();   // Ald[0..1] visible; corner/B prefetch stays in flight

// --- per-super-step work items (s0 = 2S, s1 = s0+1) ---
// MFMA cluster for step sX, reading bfr[P] (P = parity slot)
#define MFMA_STEP(SX, P)                                                       \
  {                                                                            \
    __builtin_amdgcn_s_setprio(1);                                             \
    _Pragma("unroll")                                                          \
    for (int sub = 0; sub < 4; ++sub) {                                        \
      short8 a0 = *(short8*)&Ald[(SX) & 3][((sub * 2 + 0) * 65 + lane) * 8];   \
      short8 a1 = *(short8*)&Ald[(SX) & 3][((sub * 2 + 1) * 65 + lane) * 8];   \
      acc[0] = __builtin_amdgcn_mfma_f32_32x32x16_bf16(                        \
          a0, bfr[P][sub], acc[0], 0, 0, 0);                                   \
      acc[1] = __builtin_amdgcn_mfma_f32_32x32x16_bf16(                        \
          a1, bfr[P][sub], acc[1], 0, 0, 0);                                   \
    }                                                                          \
    __builtin_amdgcn_s_setprio(0);                                             \
  }
// B-frag loads for step SX+2 into bfr[P] (must follow MFMA_STEP(SX,P))
#define BLOAD_STEP(SX, P)                                                      \
  if ((SX) + 2 < 36) {                                                         \
    int s16b = ((SX) + 2) * 4;                                                 \
    _Pragma("unroll")                                                          \
    for (int sub = 0; sub < 4; ++sub)                                          \
      bfr[P][sub] = *(const short8*)(                                          \
          Bfrag + (((size_t)(s16b + sub) * 8 + q) * 64 + lane) * 8);           \
  }
// pack corners(SX+2) -> Ald[(SX+2)&3] from cr[P]/pwt[P]
#define PACK_STEP(SX, P)                                                       \
  if ((SX) + 2 < 36)                                                           \
    pack8(cr[P][0], cr[P][1], cr[P][2], cr[P][3], pwt[P],                      \
          &Ald[((SX) + 2) & 3][wgran * 8]);
// corner loads for SX+4 -> cr[P] (must follow PACK_STEP(SX,P))
#define CLOAD_STEP(SX, P)                                                      \
  if ((SX) + 4 < 36) {                                                         \
    int s4 = (SX) + 4, t4 = s4 >> 2;                                           \
    intx4 off = sOff[t4 * 64 + sm];                                            \
    pwt[P] = sWt[t4 * 64 + sm];                                                \
    int cb = (s4 & 3) * 64 + chk * 8;                                          \
    cr[P][0] = *(const intx4*)(xb + off.x + cb);                               \
    cr[P][1] = *(const intx4*)(xb + off.y + cb);                               \
    cr[P][2] = *(const intx4*)(xb + off.z + cb);                               \
    cr[P][3] = *(const intx4*)(xb + off.w + cb);                               \
  }

  // ---- main loop: 18 super-steps x 2 K64-steps, role-skewed ----
  // Invariants at super-step S: Ald[s0&3],Ald[s1&3] packed; cr[0]=corners(s0+2),
  // cr[1]=corners(s1+2); bfr[0]=B(s0), bfr[1]=B(s1).
  for (int S = 0; S < 18; ++S) {
    int s0 = 2 * S, s1 = s0 + 1;
    if (q < 4) {
      // ROLE 0: VALU-first (pack + corner prefetch), then MFMA + B loads.
      PACK_STEP(s0, 0);
      CLOAD_STEP(s0, 0);
      PACK_STEP(s1, 1);
      CLOAD_STEP(s1, 1);
      MFMA_STEP(s0, 0);
      BLOAD_STEP(s0, 0);
      MFMA_STEP(s1, 1);
      BLOAD_STEP(s1, 1);
    } else {
      // ROLE 1: MFMA-first, then pack + corner prefetch.
      MFMA_STEP(s0, 0);
      BLOAD_STEP(s0, 0);
      MFMA_STEP(s1, 1);
      BLOAD_STEP(s1, 1);
      PACK_STEP(s0, 0);
      CLOAD_STEP(s0, 0);
      PACK_STEP(s1, 1);
      CLOAD_STEP(s1, 1);
    }
    // ONE barrier per super-step: reads {s0,s1}, writes {s0+2,s1+2} — all 4
    // buffers distinct mod 4 -> no intra-super-step hazards, either order.
    LDS_BARRIER();
  }
#undef MFMA_STEP
#undef BLOAD_STEP
#undef PACK_STEP
#undef CLOAD_STEP

  // ---- epilogue: D col = oc (lane&31), row = (r&3)+8*(r>>2)+4*(lane>>5) ----
  int oc = q * 32 + l31;
#pragma unroll
  for (int mt = 0; mt < 2; ++mt) {
    float* obase = out + (((size_t)img * OUTC + oc) << 12) + h * 64 +
                   mt * 32 + lh5 * 4;
#pragma unroll
    for (int rg = 0; rg < 4; ++rg) {
      float4 vv = make_float4(acc[mt][rg * 4 + 0], acc[mt][rg * 4 + 1],
                              acc[mt][rg * 4 + 2], acc[mt][rg * 4 + 3]);
      *(float4*)(obase + rg * 8) = vv;
    }
  }
}

// ===========================================================================
// FALLBACK PATH (round-2 kernels) — only if ws is too small (< ~9.7 MB).
// ===========================================================================
__global__ __launch_bounds__(256) void prep_fb_kernel(
    const float* __restrict__ dcn_w, const float* __restrict__ offw,
    unsigned short* __restrict__ Bw, unsigned short* __restrict__ B2w) {
  int oc = blockIdx.x;
  for (int k = threadIdx.x; k < KTOT; k += 256) {
    int t = k >> 8, c = k & 255;
    Bw[oc * KTOT + k] = f2bf(dcn_w[oc * KTOT + c * 9 + t]);
    if (oc < 32)
      B2w[oc * KTOT + k] = (oc < 27) ? f2bf(offw[oc * KTOT + c * 9 + t])
                                     : (unsigned short)0;
  }
}

__global__ __launch_bounds__(256) void conv_offset_kernel(
    const float* __restrict__ x, const unsigned short* __restrict__ B2w,
    const float* __restrict__ ob, float* __restrict__ om) {
  __shared__ unsigned short A_lds[64 * 40];
  __shared__ unsigned short B_lds[32 * 40];
  int bid = blockIdx.x;
  int n = bid >> 6, h = bid & 63;
  int tid = threadIdx.x, lane = tid & 63, q = tid >> 6;
  const float* xn = x + n * (CIN * HWSZ);
  floatx4 acc0 = {0.f, 0.f, 0.f, 0.f}, acc1 = {0.f, 0.f, 0.f, 0.f};
  int w = tid & 63, cg = tid >> 6, ocb = tid >> 3, part = tid & 7;
  for (int s = 0; s < NSTEPS; ++s) {
    int t = s >> 3, c0 = (s & 7) << 5;
    int dy = t / 3 - 1, dx = t % 3 - 1;
    __syncthreads();
    {
      int y = h + dy, xx = w + dx;
      bool inb = ((unsigned)y < 64u) && ((unsigned)xx < 64u);
      const float* xb = xn + (c0 + cg * 8) * HWSZ + y * 64 + xx;
      short8 pk;
#pragma unroll
      for (int j = 0; j < 8; ++j) { float v = inb ? xb[j * HWSZ] : 0.0f; pk[j] = (short)f2bf(v); }
      *(short8*)&A_lds[w * 40 + cg * 8] = pk;
    }
    { const unsigned short* bp = B2w + ocb * KTOT + (t << 8) + c0 + part * 4;
      *(short4v*)&B_lds[ocb * 40 + part * 4] = *(const short4v*)bp; }
    __syncthreads();
    int fr = (lane >> 4) * 8;
    short8 af  = *(short8*)&A_lds[(q * 16 + (lane & 15)) * 40 + fr];
    short8 bf0 = *(short8*)&B_lds[((lane & 15)) * 40 + fr];
    short8 bf1 = *(short8*)&B_lds[(16 + (lane & 15)) * 40 + fr];
    acc0 = __builtin_amdgcn_mfma_f32_16x16x32_bf16(af, bf0, acc0, 0, 0, 0);
    acc1 = __builtin_amdgcn_mfma_f32_16x16x32_bf16(af, bf1, acc1, 0, 0, 0);
  }
  int g = lane >> 4;
#pragma unroll
  for (int nt = 0; nt < 2; ++nt) {
    floatx4 a = nt ? acc1 : acc0;
    int oc = nt * 16 + (lane & 15);
    if (oc < 27) {
      float bias = ob[oc];
#pragma unroll
      for (int r = 0; r < 4; ++r) {
        int wm = q * 16 + g * 4 + r;
        float val = a[r] + bias;
        if (oc >= 18) val = 1.0f / (1.0f + __expf(-val));
        om[((n * 27 + oc) << 12) + h * 64 + wm] = val;
      }
    }
  }
}

__global__ __launch_bounds__(256) void dcn_main_kernel(
    const float* __restrict__ x, const float* __restrict__ om,
    const unsigned short* __restrict__ Bw, float* __restrict__ out) {
  __shared__ unsigned short A_lds[32 * 40];
  __shared__ unsigned short B_lds[256 * 40];
  __shared__ int    sY[288];
  __shared__ int    sX[288];
  __shared__ float4 sW[288];
  int bid = blockIdx.x;
  int n = bid >> 7, rem = bid & 127, h = rem >> 1, w0 = (rem & 1) << 5;
  int tid = threadIdx.x, lane = tid & 63, q = tid >> 6;
  const float* xn  = x + n * (CIN * HWSZ);
  const float* omn = om + n * (27 * HWSZ);
  for (int v = tid; v < 288; v += 256) {
    int m = v & 31, t = v >> 5;
    int ky = t / 3, kx = t % 3;
    int wg = w0 + m, sp = h * 64 + wg;
    float offy = omn[(2 * t) * HWSZ + sp];
    float offx = omn[(2 * t + 1) * HWSZ + sp];
    float mv   = omn[(18 + t) * HWSZ + sp];
    float him = (float)(h - 1 + ky) + offy;
    float wim = (float)(wg - 1 + kx) + offx;
    float y0f = floorf(him), x0f = floorf(wim);
    float lh = him - y0f, lw = wim - x0f;
    int y0 = (int)y0f, x0i = (int)x0f;
    bool vy0 = (y0 >= 0) && (y0 < HH), vy1 = (y0 + 1 >= 0) && (y0 + 1 < HH);
    bool vx0 = (x0i >= 0) && (x0i < WW), vx1 = (x0i + 1 >= 0) && (x0i + 1 < WW);
    float hh_ = 1.0f - lh, hw_ = 1.0f - lw;
    float4 wt;
    wt.x = (vy0 && vx0) ? hh_ * hw_ * mv : 0.0f;
    wt.y = (vy0 && vx1) ? hh_ * lw  * mv : 0.0f;
    wt.z = (vy1 && vx0) ? lh  * hw_ * mv : 0.0f;
    wt.w = (vy1 && vx1) ? lh  * lw  * mv : 0.0f;
    sY[v] = y0; sX[v] = x0i; sW[v] = wt;
  }
  floatx4 acc[2][4];
#pragma unroll
  for (int mi = 0; mi < 2; ++mi)
#pragma unroll
    for (int nj = 0; nj < 4; ++nj) acc[mi][nj] = (floatx4){0.f, 0.f, 0.f, 0.f};
  int m = tid & 31, cg = tid >> 5, n0 = q * 64;
  for (int s = 0; s < NSTEPS; ++s) {
    int t = s >> 3, c0 = (s & 7) << 5;
    __syncthreads();
    {
      int p = t * 32 + m;
      int y0 = sY[p], x0i = sX[p];
      float4 wt = sW[p];
      int y0c = min(max(y0, 0), 63), y1c = min(max(y0 + 1, 0), 63);
      int x0c = min(max(x0i, 0), 63), x1c = min(max(x0i + 1, 0), 63);
      int i00 = y0c * 64 + x0c, i01 = y0c * 64 + x1c;
      int i10 = y1c * 64 + x0c, i11 = y1c * 64 + x1c;
      const float* xb = xn + (c0 + cg * 4) * HWSZ;
      short4v pk;
#pragma unroll
      for (int j = 0; j < 4; ++j) {
        const float* xc = xb + j * HWSZ;
        float v = wt.x * xc[i00] + wt.y * xc[i01] + wt.z * xc[i10] + wt.w * xc[i11];
        pk[j] = (short)f2bf(v);
      }
      *(short4v*)&A_lds[m * 40 + cg * 4] = pk;
    }
    {
      const short8* bp = (const short8*)(Bw + tid * KTOT + (t << 8) + c0);
      short8 b0 = bp[0], b1 = bp[1], b2 = bp[2], b3 = bp[3];
      short8* dst = (short8*)&B_lds[tid * 40];
      dst[0] = b0; dst[1] = b1; dst[2] = b2; dst[3] = b3;
    }
    __syncthreads();
    int fr = (lane >> 4) * 8;
    short8 a0 = *(short8*)&A_lds[((lane & 15)) * 40 + fr];
    short8 a1 = *(short8*)&A_lds[(16 + (lane & 15)) * 40 + fr];
#pragma unroll
    for (int nj = 0; nj < 4; ++nj) {
      short8 bfp = *(short8*)&B_lds[(n0 + nj * 16 + (lane & 15)) * 40 + fr];
      acc[0][nj] = __builtin_amdgcn_mfma_f32_16x16x32_bf16(a0, bfp, acc[0][nj], 0, 0, 0);
      acc[1][nj] = __builtin_amdgcn_mfma_f32_16x16x32_bf16(a1, bfp, acc[1][nj], 0, 0, 0);
    }
  }
  int g = lane >> 4;
#pragma unroll
  for (int mi = 0; mi < 2; ++mi) {
    int wm = w0 + mi * 16 + g * 4;
#pragma unroll
    for (int nj = 0; nj < 4; ++nj) {
      int oc = n0 + nj * 16 + (lane & 15);
      float4 vv = make_float4(acc[mi][nj][0], acc[mi][nj][1],
                              acc[mi][nj][2], acc[mi][nj][3]);
      *(float4*)&out[((n * OUTC + oc) << 12) + h * 64 + wm] = vv;
    }
  }
}

// ---------------------------------------------------------------------------
extern "C" void kernel_launch(void* const* d_in, const int* in_sizes, int n_in,
                              void* d_out, int out_size, void* d_ws, size_t ws_size,
                              hipStream_t stream) {
  const float* x     = (const float*)d_in[0];
  const float* offw  = (const float*)d_in[1];
  const float* ob    = (const float*)d_in[2];
  const float* dcn_w = (const float*)d_in[3];
  float* out = (float*)d_out;

  if (ws_size >= (size_t)WSM_END) {
    unsigned short* Bfrag  = (unsigned short*)((char*)d_ws + WSM_BFRAG);
    unsigned short* B2frag = (unsigned short*)((char*)d_ws + WSM_B2FRAG);
    unsigned short* xtb    = (unsigned short*)((char*)d_ws + WSM_XT);
    // main path: 2 launches total
    prep_main_kernel<<<580, 256, 0, stream>>>(dcn_w, offw, x, Bfrag, B2frag, xtb);
    dcn_fused_kernel<<<256, 512, 0, stream>>>(xtb, Bfrag, B2frag, ob, out);
  } else {
    unsigned short* Bw  = (unsigned short*)((char*)d_ws + WSF_BW);
    unsigned short* B2w = (unsigned short*)((char*)d_ws + WSF_B2W);
    float*          omb = (float*)((char*)d_ws + WSF_OM);
    prep_fb_kernel<<<256, 256, 0, stream>>>(dcn_w, offw, Bw, B2w);
    conv_offset_kernel<<<NB * HH, 256, 0, stream>>>(x, B2w, ob, omb);
    dcn_main_kernel<<<NB * HH * 2, 256, 0, stream>>>(x, omb, Bw, out);
  }
}

// Round 6
// 122.793 us; speedup vs baseline: 1.0893x; 1.0051x over previous
//
#include <hip/hip_runtime.h>
#include <hip/hip_bf16.h>
#include <math.h>

// Problem constants (N, C, H, W) = (4, 256, 64, 64), out_C = 256, FS=3, pad=1, stride=1
#define NB     4
#define CIN    256
#define HH     64
#define WW     64
#define OUTC   256
#define K2     9
#define KTOT   2304                // CIN * K2
#define HWSZ   4096                // HH * WW
#define NSTEPS 72                  // KTOT / 32
#define MTOT   16384               // NB * HWSZ

// K ordering everywhere: k' = tap*256 + c (tap-major).

typedef __attribute__((ext_vector_type(4)))  float  floatx4;
typedef __attribute__((ext_vector_type(16))) float  floatx16;
typedef __attribute__((ext_vector_type(8)))  short  short8;
typedef __attribute__((ext_vector_type(4)))  short  short4v;
typedef __attribute__((ext_vector_type(4)))  int    intx4;

__device__ __forceinline__ unsigned short f2bf(float f) {
  union { float f; unsigned u; } v; v.f = f;
  unsigned r = v.u + 0x7FFF + ((v.u >> 16) & 1);   // round-to-nearest-even
  return (unsigned short)(r >> 16);
}
__device__ __forceinline__ float b2f(unsigned short s) {
  union { unsigned u; float f; } v; v.u = ((unsigned)s) << 16;
  return v.f;
}
// bf16 pair extraction from a packed u32 (2 bf16 in one dword)
__device__ __forceinline__ float lo16f(int u) {
  union { int i; float f; } v; v.i = u << 16; return v.f;
}
__device__ __forceinline__ float hi16f(int u) {
  union { int i; float f; } v; v.i = u & 0xFFFF0000; return v.f;
}
// HW packed f32->2xbf16 convert (RNE, same rounding as f2bf).
__device__ __forceinline__ unsigned cvt_pk_bf16(float lo, float hi) {
  unsigned r;
  asm("v_cvt_pk_bf16_f32 %0, %1, %2" : "=v"(r) : "v"(lo), "v"(hi));
  return r;
}

// Bilinear pack of 8 channels: 4 corner dword-quads -> 8 bf16 -> 16B LDS store.
__device__ __forceinline__ void pack8(const intx4& c0, const intx4& c1,
                                      const intx4& c2, const intx4& c3,
                                      const float4& w, unsigned short* dst) {
  intx4 o;
#pragma unroll
  for (int jj = 0; jj < 4; ++jj) {
    float v0 = w.x * lo16f(c0[jj]) + w.y * lo16f(c1[jj]) +
               w.z * lo16f(c2[jj]) + w.w * lo16f(c3[jj]);
    float v1 = w.x * hi16f(c0[jj]) + w.y * hi16f(c1[jj]) +
               w.z * hi16f(c2[jj]) + w.w * hi16f(c3[jj]);
    o[jj] = (int)cvt_pk_bf16(v0, v1);
  }
  *(intx4*)dst = o;
}

// LDS-only barrier: orders ds_write/ds_read across the workgroup WITHOUT
// draining vmcnt (global prefetch survives the barrier).
#define LDS_BARRIER() asm volatile("s_waitcnt lgkmcnt(0)\n\ts_barrier" ::: "memory")

// ---------------------------------------------------------------------------
// MAIN-PATH workspace (bytes):
//   Bfrag  : [144 s16][8 nt][64 lane][8 bf16]  = 1,179,648  (32x32x16 frag order)
//   B2frag : [72 s32][2 nt][64 lane][8 bf16]   =   147,456  (16x16x32 frag order)
//   xt     : [4][64][64][256] bf16             = 8,388,608  (channel-last x)
#define WSM_BFRAG   0
#define WSM_B2FRAG  1179648
#define WSM_XT      (1179648 + 147456)
#define WSM_END     (WSM_XT + NB * HWSZ * CIN * 2)
// FALLBACK workspace (round-2 path, only if ws is tiny):
#define WSF_BW      0
#define WSF_B2W     (KTOT * OUTC * 2)
#define WSF_OM      (WSF_B2W + KTOT * 32 * 2)
#define WSF_END     (WSF_OM + NB * 27 * HWSZ * 4)

// ---------------------------------------------------------------------------
// Kernel 0 (main): xpose (blocks 0..255) + Bfrag pack (256..543) + B2frag
// pack (544..579).  [R2 version — best measured prep]
// ---------------------------------------------------------------------------
__global__ __launch_bounds__(256) void prep_main_kernel(
    const float* __restrict__ dcn_w, const float* __restrict__ offw,
    const float* __restrict__ x,
    unsigned short* __restrict__ Bfrag, unsigned short* __restrict__ B2frag,
    unsigned short* __restrict__ xt) {
  int bid = blockIdx.x;
  int tid = threadIdx.x;
  if (bid < 256) {
    __shared__ unsigned short T[64 * 266];   // [w][c], pad 266
    int img = bid >> 6, h = bid & 63;
    const float* xp = x + (size_t)img * CIN * HWSZ + h * 64;
    int w = tid & 63, cq = tid >> 6;
    for (int cb = 0; cb < 256; cb += 4) {
      int c = cb + cq;
      T[w * 266 + c] = f2bf(xp[(size_t)c * HWSZ + w]);   // lanes=w: coalesced
    }
    __syncthreads();
    int w2 = tid >> 2, cg = (tid & 3) << 6;
    unsigned short* o = xt + ((size_t)(img * 64 + h) * 64 + w2) * 256 + cg;
#pragma unroll
    for (int i = 0; i < 64; i += 8) {
      short8 v = *(short8*)&T[w2 * 266 + cg + i];
      *(short8*)(o + i) = v;
    }
  } else if (bid < 544) {
    // Bfrag: e in [0, 73728): lane=e&63, nt=(e>>6)&7, s16=e>>9
    int e = (bid - 256) * 256 + tid;
    int lane = e & 63, nt = (e >> 6) & 7, s16 = e >> 9;
    int n = nt * 32 + (lane & 31);
    int kb = s16 * 16 + ((lane >> 5) << 3);
    short8 pk;
#pragma unroll
    for (int j = 0; j < 8; ++j) {
      int k = kb + j;
      pk[j] = (short)f2bf(dcn_w[n * KTOT + (k & 255) * 9 + (k >> 8)]);
    }
    *(short8*)(Bfrag + (size_t)e * 8) = pk;
  } else {
    // B2frag: e in [0, 9216): lane=e&63, nt=(e>>6)&1, s32=e>>7
    int e = (bid - 544) * 256 + tid;
    int lane = e & 63, nt = (e >> 6) & 1, s32 = e >> 7;
    int n = nt * 16 + (lane & 15);
    int kb = s32 * 32 + ((lane >> 4) << 3);
    short8 pk;
#pragma unroll
    for (int j = 0; j < 8; ++j) {
      int k = kb + j;
      pk[j] = (n < 27) ? (short)f2bf(offw[n * KTOT + (k & 255) * 9 + (k >> 8)])
                       : (short)0;
    }
    *(short8*)(B2frag + (size_t)e * 8) = pk;
  }
}

// ---------------------------------------------------------------------------
// Kernel 1 (main): FULLY FUSED offset-conv + sampling + GEMM, v11.
// Geometry = v8 (best measured): block = one (img,h) row, M=64, N=256,
// K=2304, grid 256 XCD-swizzled, 512 thr (8 waves, 2/SIMD). Uniform wave
// schedule (R5's role-skew reverted: neutral-to-negative, +24 VGPR).
// v11: TAP-ALIGNED 4-STEP GROUPS, ONE BARRIER PER GROUP (9 total).
// Evidence: barrier halving 36->18 bought 2.8us (~375cy each: barrier +
// lgkmcnt drain + re-convergence) — the only lever with a confirmed
// positive coefficient. Group = steps 4G..4G+3 = exactly tap G:
//  - 8-buffer Ald rotation: reads {4G..4G+3} mod 8, writes {4G+4..4G+7}
//    mod 8 — disjoint, so ONE LDS barrier per group.
//  - ONE sOff/sWt read per thread per group (shared base for 16 corner
//    loads) instead of 4 — tap-uniform within the group.
//  - corner prefetch distance 2 -> 4..8 steps; B prefetch 4 steps.
//  - group-uniform tail guards (G<8 packs/B-loads, G<7 corner loads).
// ---------------------------------------------------------------------------
__global__ __launch_bounds__(512, 2) void dcn_fused_kernel(
    const unsigned short* __restrict__ xt,
    const unsigned short* __restrict__ Bfrag,
    const unsigned short* __restrict__ B2frag,
    const float* __restrict__ ob, float* __restrict__ out) {
  __shared__ unsigned short Ald[8][520 * 8];    // 66.5 KB 8-buffer rotation
  __shared__ intx4  sOff[576];                  //  9 KB
  __shared__ float4 sWt[576];                   //  9 KB
  __shared__ float  omp[4 * 32 * 68];           // 34.8 KB conv partials
                                                // total 119.8 KB (1 blk/CU; grid==CUs)

  int braw = blockIdx.x;                // 0..255
  // XCD swizzle: XCD k (= braw%8) processes rows [k*32, (k+1)*32).
  int bid  = ((braw & 7) << 5) + (braw >> 3);
  int img = bid >> 6, h = bid & 63;
  const unsigned short* xb = xt + (size_t)img * HWSZ * 256;

  int tid  = threadIdx.x;
  int lane = tid & 63, q = tid >> 6;    // 8 waves
  int quad = lane >> 4, l15 = lane & 15;
  int l31  = lane & 31,  lh5 = lane >> 5;

  // ================= Phase A: offset conv (waves 0-3, K-split) =============
  if (q < 4) {
    floatx4 cacc[4][2];
#pragma unroll
    for (int mt = 0; mt < 4; ++mt)
#pragma unroll
      for (int nt = 0; nt < 2; ++nt) cacc[mt][nt] = (floatx4){0.f, 0.f, 0.f, 0.f};
    short8 cpa[2][4];
    short8 cpb[2][2];

#define CONV_LOAD(I, SLOT)                                                     \
  {                                                                            \
    int s = q + (I) * 4;                                                       \
    int t = s >> 3;                                                            \
    int dy = t / 3 - 1, dx = t % 3 - 1;                                        \
    int y = h + dy;                                                            \
    int cb0 = ((s & 7) << 5) + (quad << 3);                                    \
    _Pragma("unroll")                                                          \
    for (int mt = 0; mt < 4; ++mt) {                                           \
      int xx = mt * 16 + l15 + dx;                                             \
      short8 v = {0, 0, 0, 0, 0, 0, 0, 0};                                     \
      if (((unsigned)y < 64u) && ((unsigned)xx < 64u))                         \
        v = *(const short8*)(xb + ((y * 64 + xx) << 8) + cb0);                 \
      cpa[SLOT][mt] = v;                                                       \
    }                                                                          \
    _Pragma("unroll")                                                          \
    for (int nt = 0; nt < 2; ++nt)                                             \
      cpb[SLOT][nt] = *(const short8*)(B2frag + (((s * 2 + nt) * 64 + lane) << 3)); \
  }

    CONV_LOAD(0, 0);
#pragma unroll 2
    for (int i = 0; i < 18; ++i) {
      int sl = i & 1;
      if (i < 17) CONV_LOAD(i + 1, sl ^ 1);
#pragma unroll
      for (int mt = 0; mt < 4; ++mt)
#pragma unroll
        for (int nt = 0; nt < 2; ++nt)
          cacc[mt][nt] = __builtin_amdgcn_mfma_f32_16x16x32_bf16(
              cpa[sl][mt], cpb[sl][nt], cacc[mt][nt], 0, 0, 0);
    }
#undef CONV_LOAD
#pragma unroll
    for (int mt = 0; mt < 4; ++mt)
#pragma unroll
      for (int nt = 0; nt < 2; ++nt) {
        int oc = nt * 16 + l15;
        float4 vv = make_float4(cacc[mt][nt][0], cacc[mt][nt][1],
                                cacc[mt][nt][2], cacc[mt][nt][3]);
        *(float4*)&omp[(q * 32 + oc) * 68 + mt * 16 + quad * 4] = vv;
      }
  }
  __syncthreads();

  // ---- bilinear params: 9 taps x 64 w (sum 4 K-partials + bias) ----
  for (int v = tid; v < 576; v += 512) {
    int w = v & 63, t = v >> 6;
    int ky = t / 3, kx = t % 3;
    float offy = omp[(0 * 32 + 2 * t) * 68 + w] + omp[(1 * 32 + 2 * t) * 68 + w] +
                 omp[(2 * 32 + 2 * t) * 68 + w] + omp[(3 * 32 + 2 * t) * 68 + w] +
                 ob[2 * t];
    float offx = omp[(0 * 32 + 2 * t + 1) * 68 + w] + omp[(1 * 32 + 2 * t + 1) * 68 + w] +
                 omp[(2 * 32 + 2 * t + 1) * 68 + w] + omp[(3 * 32 + 2 * t + 1) * 68 + w] +
                 ob[2 * t + 1];
    float mraw = omp[(0 * 32 + 18 + t) * 68 + w] + omp[(1 * 32 + 18 + t) * 68 + w] +
                 omp[(2 * 32 + 18 + t) * 68 + w] + omp[(3 * 32 + 18 + t) * 68 + w] +
                 ob[18 + t];
    float mv   = 1.0f / (1.0f + __expf(-mraw));
    float him  = (float)(h - 1 + ky) + offy;
    float wim  = (float)(w - 1 + kx) + offx;
    float y0f = floorf(him), x0f = floorf(wim);
    float lhf = him - y0f, lwf = wim - x0f;
    int y0 = (int)y0f, x0i = (int)x0f;
    bool vy0 = (y0 >= 0) && (y0 < HH);
    bool vy1 = (y0 + 1 >= 0) && (y0 + 1 < HH);
    bool vx0 = (x0i >= 0) && (x0i < WW);
    bool vx1 = (x0i + 1 >= 0) && (x0i + 1 < WW);
    float hh_ = 1.0f - lhf, hw_ = 1.0f - lwf;
    float4 wt;
    wt.x = (vy0 && vx0) ? hh_ * hw_ * mv : 0.0f;
    wt.y = (vy0 && vx1) ? hh_ * lwf * mv : 0.0f;
    wt.z = (vy1 && vx0) ? lhf * hw_ * mv : 0.0f;
    wt.w = (vy1 && vx1) ? lhf * lwf * mv : 0.0f;
    int y0c = min(max(y0, 0), 63), y1c = min(max(y0 + 1, 0), 63);
    int x0c = min(max(x0i, 0), 63), x1c = min(max(x0i + 1, 0), 63);
    intx4 ii = {(y0c * 64 + x0c) << 8, (y0c * 64 + x1c) << 8,
                (y1c * 64 + x0c) << 8, (y1c * 64 + x1c) << 8};
    sOff[v] = ii;
    sWt[v]  = wt;
  }

  // ================= Phase B: fused sampling + GEMM ========================
  floatx16 acc[2];
#pragma unroll
  for (int mt = 0; mt < 2; ++mt)
#pragma unroll
    for (int e = 0; e < 16; ++e) acc[mt][e] = 0.f;

  int sm  = tid >> 3;          // sampler m row (0..63)
  int chk = tid & 7;           // 8-c chunk within K64 window
  // write granule: blk = sub*2 + mt, row = (chk&1)*32 + (m&31)
  int wgran = (((chk >> 1) << 1) + (sm >> 5)) * 65 + ((chk & 1) << 5) + (sm & 31);

  short8 bfr[4][4];            // B frags for the 4 steps of the current group
  intx4  cr[4][4];             // corner regs for the next group's 4 packs
  float4 pwtA, pwtN;           // pack weights: current / next group's tap

  __syncthreads();             // params ready

  // ---- prologue ----
  // B for steps 0..3:
#pragma unroll
  for (int u = 0; u < 4; ++u)
#pragma unroll
    for (int sub = 0; sub < 4; ++sub)
      bfr[u][sub] = *(const short8*)(
          Bfrag + (((size_t)(u * 4 + sub) * 8 + q) * 64 + lane) * 8);
  {
    // pack steps 0..3 (tap 0) directly into Ald[0..3]
    intx4 off0 = sOff[sm];
    float4 w0 = sWt[sm];
#pragma unroll
    for (int u = 0; u < 4; ++u) {
      int cb = u * 64 + chk * 8;
      intx4 c0 = *(const intx4*)(xb + off0.x + cb);
      intx4 c1 = *(const intx4*)(xb + off0.y + cb);
      intx4 c2 = *(const intx4*)(xb + off0.z + cb);
      intx4 c3 = *(const intx4*)(xb + off0.w + cb);
      pack8(c0, c1, c2, c3, w0, &Ald[u][wgran * 8]);
    }
    // corners for steps 4..7 (tap 1) -> cr
    intx4 off1 = sOff[64 + sm];
    pwtA = sWt[64 + sm];
    pwtN = pwtA;
#pragma unroll
    for (int u = 0; u < 4; ++u) {
      int cb = u * 64 + chk * 8;
      cr[u][0] = *(const intx4*)(xb + off1.x + cb);
      cr[u][1] = *(const intx4*)(xb + off1.y + cb);
      cr[u][2] = *(const intx4*)(xb + off1.z + cb);
      cr[u][3] = *(const intx4*)(xb + off1.w + cb);
    }
  }
  LDS_BARRIER();   // Ald[0..3] visible; tap-1 corner loads stay in flight

  // ---- main loop: 9 tap-groups x 4 K64-steps, ONE barrier per group ----
  // Invariants at group G (s0=4G): Ald[(s0..s0+3)&7] packed;
  // cr[u] = corners(s0+4+u) [issued in G-1, tap G+1]; pwtA = sWt tap G+1;
  // bfr[u] = B(s0+u).
#pragma unroll 1
  for (int G = 0; G < 9; ++G) {
    int s0 = 4 * G;
    // Phase 1: packs for steps s0+4..s0+7 (consumed by group G+1)
    if (G < 8) {
#pragma unroll
      for (int u = 0; u < 4; ++u)
        pack8(cr[u][0], cr[u][1], cr[u][2], cr[u][3], pwtA,
              &Ald[(s0 + 4 + u) & 7][wgran * 8]);
    }
    // Phase 2: corner loads for steps s0+8..s0+11 (tap G+2) — one sOff read
    if (G < 7) {
      intx4 offN = sOff[(G + 2) * 64 + sm];
      pwtN = sWt[(G + 2) * 64 + sm];
#pragma unroll
      for (int u = 0; u < 4; ++u) {
        int cb = u * 64 + chk * 8;
        cr[u][0] = *(const intx4*)(xb + offN.x + cb);
        cr[u][1] = *(const intx4*)(xb + offN.y + cb);
        cr[u][2] = *(const intx4*)(xb + offN.z + cb);
        cr[u][3] = *(const intx4*)(xb + offN.w + cb);
      }
    }
    // Phase 3: MFMA burst — steps s0..s0+3 (32 MFMA, 32 ds_reads)
    __builtin_amdgcn_s_setprio(1);
#pragma unroll
    for (int u = 0; u < 4; ++u) {
      const unsigned short* Ab = Ald[(s0 + u) & 7];
#pragma unroll
      for (int sub = 0; sub < 4; ++sub) {
        short8 a0 = *(short8*)&Ab[((sub * 2 + 0) * 65 + lane) * 8];
        short8 a1 = *(short8*)&Ab[((sub * 2 + 1) * 65 + lane) * 8];
        acc[0] = __builtin_amdgcn_mfma_f32_32x32x16_bf16(
            a0, bfr[u][sub], acc[0], 0, 0, 0);
        acc[1] = __builtin_amdgcn_mfma_f32_32x32x16_bf16(
            a1, bfr[u][sub], acc[1], 0, 0, 0);
      }
    }
    __builtin_amdgcn_s_setprio(0);
    // Phase 4: B frags for steps s0+4..s0+7 (bfr consumed in phase 3)
    if (G < 8) {
#pragma unroll
      for (int u = 0; u < 4; ++u) {
        int s16b = (s0 + 4 + u) * 4;
#pragma unroll
        for (int sub = 0; sub < 4; ++sub)
          bfr[u][sub] = *(const short8*)(
              Bfrag + (((size_t)(s16b + sub) * 8 + q) * 64 + lane) * 8);
      }
    }
    pwtA = pwtN;
    // ONE barrier per group: reads {s0..s0+3}, writes {s0+4..s0+7} — all 8
    // buffers distinct mod 8 -> no intra-group hazards.
    LDS_BARRIER();
  }

  // ---- epilogue: D col = oc (lane&31), row = (r&3)+8*(r>>2)+4*(lane>>5) ----
  int oc = q * 32 + l31;
#pragma unroll
  for (int mt = 0; mt < 2; ++mt) {
    float* obase = out + (((size_t)img * OUTC + oc) << 12) + h * 64 +
                   mt * 32 + lh5 * 4;
#pragma unroll
    for (int rg = 0; rg < 4; ++rg) {
      float4 vv = make_float4(acc[mt][rg * 4 + 0], acc[mt][rg * 4 + 1],
                              acc[mt][rg * 4 + 2], acc[mt][rg * 4 + 3]);
      *(float4*)(obase + rg * 8) = vv;
    }
  }
}

// ===========================================================================
// FALLBACK PATH (round-2 kernels) — only if ws is too small (< ~9.7 MB).
// ===========================================================================
__global__ __launch_bounds__(256) void prep_fb_kernel(
    const float* __restrict__ dcn_w, const float* __restrict__ offw,
    unsigned short* __restrict__ Bw, unsigned short* __restrict__ B2w) {
  int oc = blockIdx.x;
  for (int k = threadIdx.x; k < KTOT; k += 256) {
    int t = k >> 8, c = k & 255;
    Bw[oc * KTOT + k] = f2bf(dcn_w[oc * KTOT + c * 9 + t]);
    if (oc < 32)
      B2w[oc * KTOT + k] = (oc < 27) ? f2bf(offw[oc * KTOT + c * 9 + t])
                                     : (unsigned short)0;
  }
}

__global__ __launch_bounds__(256) void conv_offset_kernel(
    const float* __restrict__ x, const unsigned short* __restrict__ B2w,
    const float* __restrict__ ob, float* __restrict__ om) {
  __shared__ unsigned short A_lds[64 * 40];
  __shared__ unsigned short B_lds[32 * 40];
  int bid = blockIdx.x;
  int n = bid >> 6, h = bid & 63;
  int tid = threadIdx.x, lane = tid & 63, q = tid >> 6;
  const float* xn = x + n * (CIN * HWSZ);
  floatx4 acc0 = {0.f, 0.f, 0.f, 0.f}, acc1 = {0.f, 0.f, 0.f, 0.f};
  int w = tid & 63, cg = tid >> 6, ocb = tid >> 3, part = tid & 7;
  for (int s = 0; s < NSTEPS; ++s) {
    int t = s >> 3, c0 = (s & 7) << 5;
    int dy = t / 3 - 1, dx = t % 3 - 1;
    __syncthreads();
    {
      int y = h + dy, xx = w + dx;
      bool inb = ((unsigned)y < 64u) && ((unsigned)xx < 64u);
      const float* xb = xn + (c0 + cg * 8) * HWSZ + y * 64 + xx;
      short8 pk;
#pragma unroll
      for (int j = 0; j < 8; ++j) { float v = inb ? xb[j * HWSZ] : 0.0f; pk[j] = (short)f2bf(v); }
      *(short8*)&A_lds[w * 40 + cg * 8] = pk;
    }
    { const unsigned short* bp = B2w + ocb * KTOT + (t << 8) + c0 + part * 4;
      *(short4v*)&B_lds[ocb * 40 + part * 4] = *(const short4v*)bp; }
    __syncthreads();
    int fr = (lane >> 4) * 8;
    short8 af  = *(short8*)&A_lds[(q * 16 + (lane & 15)) * 40 + fr];
    short8 bf0 = *(short8*)&B_lds[((lane & 15)) * 40 + fr];
    short8 bf1 = *(short8*)&B_lds[(16 + (lane & 15)) * 40 + fr];
    acc0 = __builtin_amdgcn_mfma_f32_16x16x32_bf16(af, bf0, acc0, 0, 0, 0);
    acc1 = __builtin_amdgcn_mfma_f32_16x16x32_bf16(af, bf1, acc1, 0, 0, 0);
  }
  int g = lane >> 4;
#pragma unroll
  for (int nt = 0; nt < 2; ++nt) {
    floatx4 a = nt ? acc1 : acc0;
    int oc = nt * 16 + (lane & 15);
    if (oc < 27) {
      float bias = ob[oc];
#pragma unroll
      for (int r = 0; r < 4; ++r) {
        int wm = q * 16 + g * 4 + r;
        float val = a[r] + bias;
        if (oc >= 18) val = 1.0f / (1.0f + __expf(-val));
        om[((n * 27 + oc) << 12) + h * 64 + wm] = val;
      }
    }
  }
}

__global__ __launch_bounds__(256) void dcn_main_kernel(
    const float* __restrict__ x, const float* __restrict__ om,
    const unsigned short* __restrict__ Bw, float* __restrict__ out) {
  __shared__ unsigned short A_lds[32 * 40];
  __shared__ unsigned short B_lds[256 * 40];
  __shared__ int    sY[288];
  __shared__ int    sX[288];
  __shared__ float4 sW[288];
  int bid = blockIdx.x;
  int n = bid >> 7, rem = bid & 127, h = rem >> 1, w0 = (rem & 1) << 5;
  int tid = threadIdx.x, lane = tid & 63, q = tid >> 6;
  const float* xn  = x + n * (CIN * HWSZ);
  const float* omn = om + n * (27 * HWSZ);
  for (int v = tid; v < 288; v += 256) {
    int m = v & 31, t = v >> 5;
    int ky = t / 3, kx = t % 3;
    int wg = w0 + m, sp = h * 64 + wg;
    float offy = omn[(2 * t) * HWSZ + sp];
    float offx = omn[(2 * t + 1) * HWSZ + sp];
    float mv   = omn[(18 + t) * HWSZ + sp];
    float him = (float)(h - 1 + ky) + offy;
    float wim = (float)(wg - 1 + kx) + offx;
    float y0f = floorf(him), x0f = floorf(wim);
    float lh = him - y0f, lw = wim - x0f;
    int y0 = (int)y0f, x0i = (int)x0f;
    bool vy0 = (y0 >= 0) && (y0 < HH), vy1 = (y0 + 1 >= 0) && (y0 + 1 < HH);
    bool vx0 = (x0i >= 0) && (x0i < WW), vx1 = (x0i + 1 >= 0) && (x0i + 1 < WW);
    float hh_ = 1.0f - lh, hw_ = 1.0f - lw;
    float4 wt;
    wt.x = (vy0 && vx0) ? hh_ * hw_ * mv : 0.0f;
    wt.y = (vy0 && vx1) ? hh_ * lw  * mv : 0.0f;
    wt.z = (vy1 && vx0) ? lh  * hw_ * mv : 0.0f;
    wt.w = (vy1 && vx1) ? lh  * lw  * mv : 0.0f;
    sY[v] = y0; sX[v] = x0i; sW[v] = wt;
  }
  floatx4 acc[2][4];
#pragma unroll
  for (int mi = 0; mi < 2; ++mi)
#pragma unroll
    for (int nj = 0; nj < 4; ++nj) acc[mi][nj] = (floatx4){0.f, 0.f, 0.f, 0.f};
  int m = tid & 31, cg = tid >> 5, n0 = q * 64;
  for (int s = 0; s < NSTEPS; ++s) {
    int t = s >> 3, c0 = (s & 7) << 5;
    __syncthreads();
    {
      int p = t * 32 + m;
      int y0 = sY[p], x0i = sX[p];
      float4 wt = sW[p];
      int y0c = min(max(y0, 0), 63), y1c = min(max(y0 + 1, 0), 63);
      int x0c = min(max(x0i, 0), 63), x1c = min(max(x0i + 1, 0), 63);
      int i00 = y0c * 64 + x0c, i01 = y0c * 64 + x1c;
      int i10 = y1c * 64 + x0c, i11 = y1c * 64 + x1c;
      const float* xb = xn + (c0 + cg * 4) * HWSZ;
      short4v pk;
#pragma unroll
      for (int j = 0; j < 4; ++j) {
        const float* xc = xb + j * HWSZ;
        float v = wt.x * xc[i00] + wt.y * xc[i01] + wt.z * xc[i10] + wt.w * xc[i11];
        pk[j] = (short)f2bf(v);
      }
      *(short4v*)&A_lds[m * 40 + cg * 4] = pk;
    }
    {
      const short8* bp = (const short8*)(Bw + tid * KTOT + (t << 8) + c0);
      short8 b0 = bp[0], b1 = bp[1], b2 = bp[2], b3 = bp[3];
      short8* dst = (short8*)&B_lds[tid * 40];
      dst[0] = b0; dst[1] = b1; dst[2] = b2; dst[3] = b3;
    }
    __syncthreads();
    int fr = (lane >> 4) * 8;
    short8 a0 = *(short8*)&A_lds[((lane & 15)) * 40 + fr];
    short8 a1 = *(short8*)&A_lds[(16 + (lane & 15)) * 40 + fr];
#pragma unroll
    for (int nj = 0; nj < 4; ++nj) {
      short8 bfp = *(short8*)&B_lds[(n0 + nj * 16 + (lane & 15)) * 40 + fr];
      acc[0][nj] = __builtin_amdgcn_mfma_f32_16x16x32_bf16(a0, bfp, acc[0][nj], 0, 0, 0);
      acc[1][nj] = __builtin_amdgcn_mfma_f32_16x16x32_bf16(a1, bfp, acc[1][nj], 0, 0, 0);
    }
  }
  int g = lane >> 4;
#pragma unroll
  for (int mi = 0; mi < 2; ++mi) {
    int wm = w0 + mi * 16 + g * 4;
#pragma unroll
    for (int nj = 0; nj < 4; ++nj) {
      int oc = n0 + nj * 16 + (lane & 15);
      float4 vv = make_float4(acc[mi][nj][0], acc[mi][nj][1],
                              acc[mi][nj][2], acc[mi][nj][3]);
      *(float4*)&out[((n * OUTC + oc) << 12) + h * 64 + wm] = vv;
    }
  }
}

// ---------------------------------------------------------------------------
extern "C" void kernel_launch(void* const* d_in, const int* in_sizes, int n_in,
                              void* d_out, int out_size, void* d_ws, size_t ws_size,
                              hipStream_t stream) {
  const float* x     = (const float*)d_in[0];
  const float* offw  = (const float*)d_in[1];
  const float* ob    = (const float*)d_in[2];
  const float* dcn_w = (const float*)d_in[3];
  float* out = (float*)d_out;

  if (ws_size >= (size_t)WSM_END) {
    unsigned short* Bfrag  = (unsigned short*)((char*)d_ws + WSM_BFRAG);
    unsigned short* B2frag = (unsigned short*)((char*)d_ws + WSM_B2FRAG);
    unsigned short* xtb    = (unsigned short*)((char*)d_ws + WSM_XT);
    // main path: 2 launches total
    prep_main_kernel<<<580, 256, 0, stream>>>(dcn_w, offw, x, Bfrag, B2frag, xtb);
    dcn_fused_kernel<<<256, 512, 0, stream>>>(xtb, Bfrag, B2frag, ob, out);
  } else {
    unsigned short* Bw  = (unsigned short*)((char*)d_ws + WSF_BW);
    unsigned short* B2w = (unsigned short*)((char*)d_ws + WSF_B2W);
    float*          omb = (float*)((char*)d_ws + WSF_OM);
    prep_fb_kernel<<<256, 256, 0, stream>>>(dcn_w, offw, Bw, B2w);
    conv_offset_kernel<<<NB * HH, 256, 0, stream>>>(x, B2w, ob, omb);
    dcn_main_kernel<<<NB * HH * 2, 256, 0, stream>>>(x, omb, Bw, out);
  }
}

// Round 7
// 121.537 us; speedup vs baseline: 1.1006x; 1.0103x over previous
//
#include <hip/hip_runtime.h>
#include <hip/hip_bf16.h>
#include <math.h>

// Problem constants (N, C, H, W) = (4, 256, 64, 64), out_C = 256, FS=3, pad=1, stride=1
#define NB     4
#define CIN    256
#define HH     64
#define WW     64
#define OUTC   256
#define K2     9
#define KTOT   2304                // CIN * K2
#define HWSZ   4096                // HH * WW
#define NSTEPS 72                  // KTOT / 32
#define MTOT   16384               // NB * HWSZ

// K ordering everywhere: k' = tap*256 + c (tap-major).

typedef __attribute__((ext_vector_type(2)))  float  floatx2;
typedef __attribute__((ext_vector_type(4)))  float  floatx4;
typedef __attribute__((ext_vector_type(16))) float  floatx16;
typedef __attribute__((ext_vector_type(8)))  short  short8;
typedef __attribute__((ext_vector_type(4)))  short  short4v;
typedef __attribute__((ext_vector_type(4)))  int    intx4;

__device__ __forceinline__ unsigned short f2bf(float f) {
  union { float f; unsigned u; } v; v.f = f;
  unsigned r = v.u + 0x7FFF + ((v.u >> 16) & 1);   // round-to-nearest-even
  return (unsigned short)(r >> 16);
}
__device__ __forceinline__ float b2f(unsigned short s) {
  union { unsigned u; float f; } v; v.u = ((unsigned)s) << 16;
  return v.f;
}
// bf16 pair extraction from a packed u32 (2 bf16 in one dword)
__device__ __forceinline__ float lo16f(int u) {
  union { int i; float f; } v; v.i = u << 16; return v.f;
}
__device__ __forceinline__ float hi16f(int u) {
  union { int i; float f; } v; v.i = u & 0xFFFF0000; return v.f;
}
// HW packed f32->2xbf16 convert (RNE, same rounding as f2bf).
__device__ __forceinline__ unsigned cvt_pk_bf16(float lo, float hi) {
  unsigned r;
  asm("v_cvt_pk_bf16_f32 %0, %1, %2" : "=v"(r) : "v"(lo), "v"(hi));
  return r;
}
// Packed 2xf32 FMA (VOP3P) — d = a*b + c per channel.
__device__ __forceinline__ floatx2 pk_fma(floatx2 a, floatx2 b, floatx2 c) {
  floatx2 d;
  asm("v_pk_fma_f32 %0, %1, %2, %3" : "=v"(d) : "v"(a), "v"(b), "v"(c));
  return d;
}

// Bilinear pack of 8 channels: 4 corner dword-quads -> 8 bf16 -> 16B LDS store.
// v12: v_pk_fma_f32 — per dword: 8 extracts + 4 pk_fma + 1 cvt_pk (13 VALU)
// vs scalar 8 extracts + 8 fma + 1 cvt (17). Pack was the largest VALU item
// in the serial-pipe-sum model (~900cy/step VALU).
__device__ __forceinline__ void pack8(const intx4& c0, const intx4& c1,
                                      const intx4& c2, const intx4& c3,
                                      const float4& w, unsigned short* dst) {
  floatx2 w0 = {w.x, w.x}, w1 = {w.y, w.y}, w2 = {w.z, w.z}, w3 = {w.w, w.w};
  intx4 o;
#pragma unroll
  for (int jj = 0; jj < 4; ++jj) {
    floatx2 p0 = {lo16f(c0[jj]), hi16f(c0[jj])};
    floatx2 p1 = {lo16f(c1[jj]), hi16f(c1[jj])};
    floatx2 p2 = {lo16f(c2[jj]), hi16f(c2[jj])};
    floatx2 p3 = {lo16f(c3[jj]), hi16f(c3[jj])};
    floatx2 a = {0.f, 0.f};
    a = pk_fma(w0, p0, a);
    a = pk_fma(w1, p1, a);
    a = pk_fma(w2, p2, a);
    a = pk_fma(w3, p3, a);
    o[jj] = (int)cvt_pk_bf16(a[0], a[1]);
  }
  *(intx4*)dst = o;
}

// LDS-only barrier: orders ds_write/ds_read across the workgroup WITHOUT
// draining vmcnt (global prefetch survives the barrier).
#define LDS_BARRIER() asm volatile("s_waitcnt lgkmcnt(0)\n\ts_barrier" ::: "memory")

// ---------------------------------------------------------------------------
// MAIN-PATH workspace (bytes):
//   Bfrag  : [144 s16][8 nt][64 lane][8 bf16]  = 1,179,648  (32x32x16 frag order)
//   B2frag : [72 s32][2 nt][64 lane][8 bf16]   =   147,456  (16x16x32 frag order)
//   xt     : [4][64][64][256] bf16             = 8,388,608  (channel-last x)
#define WSM_BFRAG   0
#define WSM_B2FRAG  1179648
#define WSM_XT      (1179648 + 147456)
#define WSM_END     (WSM_XT + NB * HWSZ * CIN * 2)
// FALLBACK workspace (round-2 path, only if ws is tiny):
#define WSF_BW      0
#define WSF_B2W     (KTOT * OUTC * 2)
#define WSF_OM      (WSF_B2W + KTOT * 32 * 2)
#define WSF_END     (WSF_OM + NB * 27 * HWSZ * 4)

// ---------------------------------------------------------------------------
// Kernel 0 (main): xpose (blocks 0..255) + Bfrag pack (256..543) + B2frag
// pack (544..579).  [R2 version — best measured prep]
// ---------------------------------------------------------------------------
__global__ __launch_bounds__(256) void prep_main_kernel(
    const float* __restrict__ dcn_w, const float* __restrict__ offw,
    const float* __restrict__ x,
    unsigned short* __restrict__ Bfrag, unsigned short* __restrict__ B2frag,
    unsigned short* __restrict__ xt) {
  int bid = blockIdx.x;
  int tid = threadIdx.x;
  if (bid < 256) {
    __shared__ unsigned short T[64 * 266];   // [w][c], pad 266
    int img = bid >> 6, h = bid & 63;
    const float* xp = x + (size_t)img * CIN * HWSZ + h * 64;
    int w = tid & 63, cq = tid >> 6;
    for (int cb = 0; cb < 256; cb += 4) {
      int c = cb + cq;
      T[w * 266 + c] = f2bf(xp[(size_t)c * HWSZ + w]);   // lanes=w: coalesced
    }
    __syncthreads();
    int w2 = tid >> 2, cg = (tid & 3) << 6;
    unsigned short* o = xt + ((size_t)(img * 64 + h) * 64 + w2) * 256 + cg;
#pragma unroll
    for (int i = 0; i < 64; i += 8) {
      short8 v = *(short8*)&T[w2 * 266 + cg + i];
      *(short8*)(o + i) = v;
    }
  } else if (bid < 544) {
    // Bfrag: e in [0, 73728): lane=e&63, nt=(e>>6)&7, s16=e>>9
    int e = (bid - 256) * 256 + tid;
    int lane = e & 63, nt = (e >> 6) & 7, s16 = e >> 9;
    int n = nt * 32 + (lane & 31);
    int kb = s16 * 16 + ((lane >> 5) << 3);
    short8 pk;
#pragma unroll
    for (int j = 0; j < 8; ++j) {
      int k = kb + j;
      pk[j] = (short)f2bf(dcn_w[n * KTOT + (k & 255) * 9 + (k >> 8)]);
    }
    *(short8*)(Bfrag + (size_t)e * 8) = pk;
  } else {
    // B2frag: e in [0, 9216): lane=e&63, nt=(e>>6)&1, s32=e>>7
    int e = (bid - 544) * 256 + tid;
    int lane = e & 63, nt = (e >> 6) & 1, s32 = e >> 7;
    int n = nt * 16 + (lane & 15);
    int kb = s32 * 32 + ((lane >> 4) << 3);
    short8 pk;
#pragma unroll
    for (int j = 0; j < 8; ++j) {
      int k = kb + j;
      pk[j] = (n < 27) ? (short)f2bf(offw[n * KTOT + (k & 255) * 9 + (k >> 8)])
                       : (short)0;
    }
    *(short8*)(B2frag + (size_t)e * 8) = pk;
  }
}

// ---------------------------------------------------------------------------
// Kernel 1 (main): FULLY FUSED offset-conv + sampling + GEMM, v12.
// EXACT v8 structure (best measured: 49.3us) — block = one (img,h) row,
// M=64, N=256, K=2304, grid 256 XCD-swizzled, 512 thr (8 waves, 2/SIMD),
// 4-buffer Ald rotation, ONE LDS-only barrier per 2-step super-step,
// setprio around MFMA, uniform wave schedule. Only change vs v8: pack8
// uses v_pk_fma_f32 (see above).
// Model (closed in R6): per K64-step the pipes sum serially —
// VMEM ~1000cy + VALU ~900 + LDS ~560 (8 waves re-read the full A tile)
// + MFMA ~510 ~= measured 3285cy/step. All overlap levers (vmcnt-
// preserving barriers R1, L2 locality R2, super-steps R3, block TLP R4,
// wave skew R5, tap groups R6) measured <=0 except super-steps (-2.8us).
// This round shrinks the VALU addend.
// ---------------------------------------------------------------------------
__global__ __launch_bounds__(512, 2) void dcn_fused_kernel(
    const unsigned short* __restrict__ xt,
    const unsigned short* __restrict__ Bfrag,
    const unsigned short* __restrict__ B2frag,
    const float* __restrict__ ob, float* __restrict__ out) {
  __shared__ unsigned short Ald[4][520 * 8];    // 16.6 KB 4-buffer rotation
  __shared__ intx4  sOff[576];                  //  9 KB
  __shared__ float4 sWt[576];                   //  9 KB
  __shared__ float  omp[4 * 32 * 68];           // 34.8 KB conv partials

  int braw = blockIdx.x;                // 0..255
  // XCD swizzle: XCD k (= braw%8) processes rows [k*32, (k+1)*32).
  int bid  = ((braw & 7) << 5) + (braw >> 3);
  int img = bid >> 6, h = bid & 63;
  const unsigned short* xb = xt + (size_t)img * HWSZ * 256;

  int tid  = threadIdx.x;
  int lane = tid & 63, q = tid >> 6;    // 8 waves
  int quad = lane >> 4, l15 = lane & 15;
  int l31  = lane & 31,  lh5 = lane >> 5;

  // ================= Phase A: offset conv (waves 0-3, K-split) =============
  if (q < 4) {
    floatx4 cacc[4][2];
#pragma unroll
    for (int mt = 0; mt < 4; ++mt)
#pragma unroll
      for (int nt = 0; nt < 2; ++nt) cacc[mt][nt] = (floatx4){0.f, 0.f, 0.f, 0.f};
    short8 cpa[2][4];
    short8 cpb[2][2];

#define CONV_LOAD(I, SLOT)                                                     \
  {                                                                            \
    int s = q + (I) * 4;                                                       \
    int t = s >> 3;                                                            \
    int dy = t / 3 - 1, dx = t % 3 - 1;                                        \
    int y = h + dy;                                                            \
    int cb0 = ((s & 7) << 5) + (quad << 3);                                    \
    _Pragma("unroll")                                                          \
    for (int mt = 0; mt < 4; ++mt) {                                           \
      int xx = mt * 16 + l15 + dx;                                             \
      short8 v = {0, 0, 0, 0, 0, 0, 0, 0};                                     \
      if (((unsigned)y < 64u) && ((unsigned)xx < 64u))                         \
        v = *(const short8*)(xb + ((y * 64 + xx) << 8) + cb0);                 \
      cpa[SLOT][mt] = v;                                                       \
    }                                                                          \
    _Pragma("unroll")                                                          \
    for (int nt = 0; nt < 2; ++nt)                                             \
      cpb[SLOT][nt] = *(const short8*)(B2frag + (((s * 2 + nt) * 64 + lane) << 3)); \
  }

    CONV_LOAD(0, 0);
#pragma unroll 2
    for (int i = 0; i < 18; ++i) {
      int sl = i & 1;
      if (i < 17) CONV_LOAD(i + 1, sl ^ 1);
#pragma unroll
      for (int mt = 0; mt < 4; ++mt)
#pragma unroll
        for (int nt = 0; nt < 2; ++nt)
          cacc[mt][nt] = __builtin_amdgcn_mfma_f32_16x16x32_bf16(
              cpa[sl][mt], cpb[sl][nt], cacc[mt][nt], 0, 0, 0);
    }
#undef CONV_LOAD
#pragma unroll
    for (int mt = 0; mt < 4; ++mt)
#pragma unroll
      for (int nt = 0; nt < 2; ++nt) {
        int oc = nt * 16 + l15;
        float4 vv = make_float4(cacc[mt][nt][0], cacc[mt][nt][1],
                                cacc[mt][nt][2], cacc[mt][nt][3]);
        *(float4*)&omp[(q * 32 + oc) * 68 + mt * 16 + quad * 4] = vv;
      }
  }
  __syncthreads();

  // ---- bilinear params: 9 taps x 64 w (sum 4 K-partials + bias) ----
  for (int v = tid; v < 576; v += 512) {
    int w = v & 63, t = v >> 6;
    int ky = t / 3, kx = t % 3;
    float offy = omp[(0 * 32 + 2 * t) * 68 + w] + omp[(1 * 32 + 2 * t) * 68 + w] +
                 omp[(2 * 32 + 2 * t) * 68 + w] + omp[(3 * 32 + 2 * t) * 68 + w] +
                 ob[2 * t];
    float offx = omp[(0 * 32 + 2 * t + 1) * 68 + w] + omp[(1 * 32 + 2 * t + 1) * 68 + w] +
                 omp[(2 * 32 + 2 * t + 1) * 68 + w] + omp[(3 * 32 + 2 * t + 1) * 68 + w] +
                 ob[2 * t + 1];
    float mraw = omp[(0 * 32 + 18 + t) * 68 + w] + omp[(1 * 32 + 18 + t) * 68 + w] +
                 omp[(2 * 32 + 18 + t) * 68 + w] + omp[(3 * 32 + 18 + t) * 68 + w] +
                 ob[18 + t];
    float mv   = 1.0f / (1.0f + __expf(-mraw));
    float him  = (float)(h - 1 + ky) + offy;
    float wim  = (float)(w - 1 + kx) + offx;
    float y0f = floorf(him), x0f = floorf(wim);
    float lhf = him - y0f, lwf = wim - x0f;
    int y0 = (int)y0f, x0i = (int)x0f;
    bool vy0 = (y0 >= 0) && (y0 < HH);
    bool vy1 = (y0 + 1 >= 0) && (y0 + 1 < HH);
    bool vx0 = (x0i >= 0) && (x0i < WW);
    bool vx1 = (x0i + 1 >= 0) && (x0i + 1 < WW);
    float hh_ = 1.0f - lhf, hw_ = 1.0f - lwf;
    float4 wt;
    wt.x = (vy0 && vx0) ? hh_ * hw_ * mv : 0.0f;
    wt.y = (vy0 && vx1) ? hh_ * lwf * mv : 0.0f;
    wt.z = (vy1 && vx0) ? lhf * hw_ * mv : 0.0f;
    wt.w = (vy1 && vx1) ? lhf * lwf * mv : 0.0f;
    int y0c = min(max(y0, 0), 63), y1c = min(max(y0 + 1, 0), 63);
    int x0c = min(max(x0i, 0), 63), x1c = min(max(x0i + 1, 0), 63);
    intx4 ii = {(y0c * 64 + x0c) << 8, (y0c * 64 + x1c) << 8,
                (y1c * 64 + x0c) << 8, (y1c * 64 + x1c) << 8};
    sOff[v] = ii;
    sWt[v]  = wt;
  }

  // ================= Phase B: fused sampling + GEMM ========================
  floatx16 acc[2];
#pragma unroll
  for (int mt = 0; mt < 2; ++mt)
#pragma unroll
    for (int e = 0; e < 16; ++e) acc[mt][e] = 0.f;

  int sm  = tid >> 3;          // sampler m row (0..63)
  int chk = tid & 7;           // 8-c chunk within K64 window
  // write granule: blk = sub*2 + mt, row = (chk&1)*32 + (m&31)
  int wgran = (((chk >> 1) << 1) + (sm >> 5)) * 65 + ((chk & 1) << 5) + (sm & 31);

  short8 bfr[2][4];            // B frags [step parity][sub]
  intx4  cr[2][4];             // corner regs, slot = (target step) & 1
  float4 pwt[2];               // weights matching cr slots

  __syncthreads();             // params ready

  // ---- prologue: pack steps 0,1; prefetch corners 2,3; B 0,1 ----
#pragma unroll
  for (int sub = 0; sub < 4; ++sub) {
    bfr[0][sub] = *(const short8*)(
        Bfrag + (((size_t)(0 + sub) * 8 + q) * 64 + lane) * 8);
    bfr[1][sub] = *(const short8*)(
        Bfrag + (((size_t)(4 + sub) * 8 + q) * 64 + lane) * 8);
  }
  {
    intx4 off = sOff[sm];
    float4 w0 = sWt[sm];
    {
      int cb = chk * 8;                      // s=0
      intx4 c0 = *(const intx4*)(xb + off.x + cb);
      intx4 c1 = *(const intx4*)(xb + off.y + cb);
      intx4 c2 = *(const intx4*)(xb + off.z + cb);
      intx4 c3 = *(const intx4*)(xb + off.w + cb);
      pack8(c0, c1, c2, c3, w0, &Ald[0][wgran * 8]);
    }
    {
      int cb = 64 + chk * 8;                 // s=1
      intx4 c0 = *(const intx4*)(xb + off.x + cb);
      intx4 c1 = *(const intx4*)(xb + off.y + cb);
      intx4 c2 = *(const intx4*)(xb + off.z + cb);
      intx4 c3 = *(const intx4*)(xb + off.w + cb);
      pack8(c0, c1, c2, c3, w0, &Ald[1][wgran * 8]);
    }
    {
      int cb = 128 + chk * 8;                // s=2 -> cr[0]
      pwt[0] = w0;
      cr[0][0] = *(const intx4*)(xb + off.x + cb);
      cr[0][1] = *(const intx4*)(xb + off.y + cb);
      cr[0][2] = *(const intx4*)(xb + off.z + cb);
      cr[0][3] = *(const intx4*)(xb + off.w + cb);
    }
    {
      int cb = 192 + chk * 8;                // s=3 -> cr[1]
      pwt[1] = w0;
      cr[1][0] = *(const intx4*)(xb + off.x + cb);
      cr[1][1] = *(const intx4*)(xb + off.y + cb);
      cr[1][2] = *(const intx4*)(xb + off.z + cb);
      cr[1][3] = *(const intx4*)(xb + off.w + cb);
    }
  }
  LDS_BARRIER();   // Ald[0..1] visible; corner/B prefetch stays in flight

  // ---- main loop: 18 super-steps x 2 K64-steps ----
  // Invariants at super-step S (s0=2S): Ald[s0&3],Ald[s1&3] packed;
  // cr[0]=corners(s0+2), cr[1]=corners(s0+3); bfr[0]=B(s0), bfr[1]=B(s1).
#pragma unroll 2
  for (int S = 0; S < 18; ++S) {
    int s0 = 2 * S, s1 = s0 + 1;
    // ---- half 0: MFMA(s0) ----
    __builtin_amdgcn_s_setprio(1);
#pragma unroll
    for (int sub = 0; sub < 4; ++sub) {
      short8 a0 = *(short8*)&Ald[s0 & 3][((sub * 2 + 0) * 65 + lane) * 8];
      short8 a1 = *(short8*)&Ald[s0 & 3][((sub * 2 + 1) * 65 + lane) * 8];
      acc[0] = __builtin_amdgcn_mfma_f32_32x32x16_bf16(
          a0, bfr[0][sub], acc[0], 0, 0, 0);
      acc[1] = __builtin_amdgcn_mfma_f32_32x32x16_bf16(
          a1, bfr[0][sub], acc[1], 0, 0, 0);
    }
    __builtin_amdgcn_s_setprio(0);
    if (s0 + 2 < 36) {
      // B frags for s0+2 -> bfr[0] (consumed after next barrier)
      int s16b = (s0 + 2) * 4;
#pragma unroll
      for (int sub = 0; sub < 4; ++sub)
        bfr[0][sub] = *(const short8*)(
            Bfrag + (((size_t)(s16b + sub) * 8 + q) * 64 + lane) * 8);
      // pack corners(s0+2) -> Ald[(s0+2)&3] (read next super-step)
      pack8(cr[0][0], cr[0][1], cr[0][2], cr[0][3], pwt[0],
            &Ald[(s0 + 2) & 3][wgran * 8]);
    }
    if (s0 + 4 < 36) {
      // corner loads for s0+4 -> freed cr[0]
      int s4 = s0 + 4, t4 = s4 >> 2;
      intx4 off = sOff[t4 * 64 + sm];
      pwt[0] = sWt[t4 * 64 + sm];
      int cb = (s4 & 3) * 64 + chk * 8;
      cr[0][0] = *(const intx4*)(xb + off.x + cb);
      cr[0][1] = *(const intx4*)(xb + off.y + cb);
      cr[0][2] = *(const intx4*)(xb + off.z + cb);
      cr[0][3] = *(const intx4*)(xb + off.w + cb);
    }
    // ---- half 1: MFMA(s1) ----
    __builtin_amdgcn_s_setprio(1);
#pragma unroll
    for (int sub = 0; sub < 4; ++sub) {
      short8 a0 = *(short8*)&Ald[s1 & 3][((sub * 2 + 0) * 65 + lane) * 8];
      short8 a1 = *(short8*)&Ald[s1 & 3][((sub * 2 + 1) * 65 + lane) * 8];
      acc[0] = __builtin_amdgcn_mfma_f32_32x32x16_bf16(
          a0, bfr[1][sub], acc[0], 0, 0, 0);
      acc[1] = __builtin_amdgcn_mfma_f32_32x32x16_bf16(
          a1, bfr[1][sub], acc[1], 0, 0, 0);
    }
    __builtin_amdgcn_s_setprio(0);
    if (s1 + 2 < 36) {
      int s16b = (s1 + 2) * 4;
#pragma unroll
      for (int sub = 0; sub < 4; ++sub)
        bfr[1][sub] = *(const short8*)(
            Bfrag + (((size_t)(s16b + sub) * 8 + q) * 64 + lane) * 8);
      pack8(cr[1][0], cr[1][1], cr[1][2], cr[1][3], pwt[1],
            &Ald[(s1 + 2) & 3][wgran * 8]);
    }
    if (s1 + 4 < 36) {
      int s4 = s1 + 4, t4 = s4 >> 2;
      intx4 off = sOff[t4 * 64 + sm];
      pwt[1] = sWt[t4 * 64 + sm];
      int cb = (s4 & 3) * 64 + chk * 8;
      cr[1][0] = *(const intx4*)(xb + off.x + cb);
      cr[1][1] = *(const intx4*)(xb + off.y + cb);
      cr[1][2] = *(const intx4*)(xb + off.z + cb);
      cr[1][3] = *(const intx4*)(xb + off.w + cb);
    }
    // ONE barrier per super-step: {s0,s1} reads and {s0+2,s0+3} writes hit
    // 4 distinct buffers mod 4 -> no intra-super-step hazards.
    LDS_BARRIER();
  }

  // ---- epilogue: D col = oc (lane&31), row = (r&3)+8*(r>>2)+4*(lane>>5) ----
  int oc = q * 32 + l31;
#pragma unroll
  for (int mt = 0; mt < 2; ++mt) {
    float* obase = out + (((size_t)img * OUTC + oc) << 12) + h * 64 +
                   mt * 32 + lh5 * 4;
#pragma unroll
    for (int rg = 0; rg < 4; ++rg) {
      float4 vv = make_float4(acc[mt][rg * 4 + 0], acc[mt][rg * 4 + 1],
                              acc[mt][rg * 4 + 2], acc[mt][rg * 4 + 3]);
      *(float4*)(obase + rg * 8) = vv;
    }
  }
}

// ===========================================================================
// FALLBACK PATH (round-2 kernels) — only if ws is too small (< ~9.7 MB).
// ===========================================================================
__global__ __launch_bounds__(256) void prep_fb_kernel(
    const float* __restrict__ dcn_w, const float* __restrict__ offw,
    unsigned short* __restrict__ Bw, unsigned short* __restrict__ B2w) {
  int oc = blockIdx.x;
  for (int k = threadIdx.x; k < KTOT; k += 256) {
    int t = k >> 8, c = k & 255;
    Bw[oc * KTOT + k] = f2bf(dcn_w[oc * KTOT + c * 9 + t]);
    if (oc < 32)
      B2w[oc * KTOT + k] = (oc < 27) ? f2bf(offw[oc * KTOT + c * 9 + t])
                                     : (unsigned short)0;
  }
}

__global__ __launch_bounds__(256) void conv_offset_kernel(
    const float* __restrict__ x, const unsigned short* __restrict__ B2w,
    const float* __restrict__ ob, float* __restrict__ om) {
  __shared__ unsigned short A_lds[64 * 40];
  __shared__ unsigned short B_lds[32 * 40];
  int bid = blockIdx.x;
  int n = bid >> 6, h = bid & 63;
  int tid = threadIdx.x, lane = tid & 63, q = tid >> 6;
  const float* xn = x + n * (CIN * HWSZ);
  floatx4 acc0 = {0.f, 0.f, 0.f, 0.f}, acc1 = {0.f, 0.f, 0.f, 0.f};
  int w = tid & 63, cg = tid >> 6, ocb = tid >> 3, part = tid & 7;
  for (int s = 0; s < NSTEPS; ++s) {
    int t = s >> 3, c0 = (s & 7) << 5;
    int dy = t / 3 - 1, dx = t % 3 - 1;
    __syncthreads();
    {
      int y = h + dy, xx = w + dx;
      bool inb = ((unsigned)y < 64u) && ((unsigned)xx < 64u);
      const float* xb = xn + (c0 + cg * 8) * HWSZ + y * 64 + xx;
      short8 pk;
#pragma unroll
      for (int j = 0; j < 8; ++j) { float v = inb ? xb[j * HWSZ] : 0.0f; pk[j] = (short)f2bf(v); }
      *(short8*)&A_lds[w * 40 + cg * 8] = pk;
    }
    { const unsigned short* bp = B2w + ocb * KTOT + (t << 8) + c0 + part * 4;
      *(short4v*)&B_lds[ocb * 40 + part * 4] = *(const short4v*)bp; }
    __syncthreads();
    int fr = (lane >> 4) * 8;
    short8 af  = *(short8*)&A_lds[(q * 16 + (lane & 15)) * 40 + fr];
    short8 bf0 = *(short8*)&B_lds[((lane & 15)) * 40 + fr];
    short8 bf1 = *(short8*)&B_lds[(16 + (lane & 15)) * 40 + fr];
    acc0 = __builtin_amdgcn_mfma_f32_16x16x32_bf16(af, bf0, acc0, 0, 0, 0);
    acc1 = __builtin_amdgcn_mfma_f32_16x16x32_bf16(af, bf1, acc1, 0, 0, 0);
  }
  int g = lane >> 4;
#pragma unroll
  for (int nt = 0; nt < 2; ++nt) {
    floatx4 a = nt ? acc1 : acc0;
    int oc = nt * 16 + (lane & 15);
    if (oc < 27) {
      float bias = ob[oc];
#pragma unroll
      for (int r = 0; r < 4; ++r) {
        int wm = q * 16 + g * 4 + r;
        float val = a[r] + bias;
        if (oc >= 18) val = 1.0f / (1.0f + __expf(-val));
        om[((n * 27 + oc) << 12) + h * 64 + wm] = val;
      }
    }
  }
}

__global__ __launch_bounds__(256) void dcn_main_kernel(
    const float* __restrict__ x, const float* __restrict__ om,
    const unsigned short* __restrict__ Bw, float* __restrict__ out) {
  __shared__ unsigned short A_lds[32 * 40];
  __shared__ unsigned short B_lds[256 * 40];
  __shared__ int    sY[288];
  __shared__ int    sX[288];
  __shared__ float4 sW[288];
  int bid = blockIdx.x;
  int n = bid >> 7, rem = bid & 127, h = rem >> 1, w0 = (rem & 1) << 5;
  int tid = threadIdx.x, lane = tid & 63, q = tid >> 6;
  const float* xn  = x + n * (CIN * HWSZ);
  const float* omn = om + n * (27 * HWSZ);
  for (int v = tid; v < 288; v += 256) {
    int m = v & 31, t = v >> 5;
    int ky = t / 3, kx = t % 3;
    int wg = w0 + m, sp = h * 64 + wg;
    float offy = omn[(2 * t) * HWSZ + sp];
    float offx = omn[(2 * t + 1) * HWSZ + sp];
    float mv   = omn[(18 + t) * HWSZ + sp];
    float him = (float)(h - 1 + ky) + offy;
    float wim = (float)(wg - 1 + kx) + offx;
    float y0f = floorf(him), x0f = floorf(wim);
    float lh = him - y0f, lw = wim - x0f;
    int y0 = (int)y0f, x0i = (int)x0f;
    bool vy0 = (y0 >= 0) && (y0 < HH), vy1 = (y0 + 1 >= 0) && (y0 + 1 < HH);
    bool vx0 = (x0i >= 0) && (x0i < WW), vx1 = (x0i + 1 >= 0) && (x0i + 1 < WW);
    float hh_ = 1.0f - lh, hw_ = 1.0f - lw;
    float4 wt;
    wt.x = (vy0 && vx0) ? hh_ * hw_ * mv : 0.0f;
    wt.y = (vy0 && vx1) ? hh_ * lw  * mv : 0.0f;
    wt.z = (vy1 && vx0) ? lh  * hw_ * mv : 0.0f;
    wt.w = (vy1 && vx1) ? lh  * lw  * mv : 0.0f;
    sY[v] = y0; sX[v] = x0i; sW[v] = wt;
  }
  floatx4 acc[2][4];
#pragma unroll
  for (int mi = 0; mi < 2; ++mi)
#pragma unroll
    for (int nj = 0; nj < 4; ++nj) acc[mi][nj] = (floatx4){0.f, 0.f, 0.f, 0.f};
  int m = tid & 31, cg = tid >> 5, n0 = q * 64;
  for (int s = 0; s < NSTEPS; ++s) {
    int t = s >> 3, c0 = (s & 7) << 5;
    __syncthreads();
    {
      int p = t * 32 + m;
      int y0 = sY[p], x0i = sX[p];
      float4 wt = sW[p];
      int y0c = min(max(y0, 0), 63), y1c = min(max(y0 + 1, 0), 63);
      int x0c = min(max(x0i, 0), 63), x1c = min(max(x0i + 1, 0), 63);
      int i00 = y0c * 64 + x0c, i01 = y0c * 64 + x1c;
      int i10 = y1c * 64 + x0c, i11 = y1c * 64 + x1c;
      const float* xb = xn + (c0 + cg * 4) * HWSZ;
      short4v pk;
#pragma unroll
      for (int j = 0; j < 4; ++j) {
        const float* xc = xb + j * HWSZ;
        float v = wt.x * xc[i00] + wt.y * xc[i01] + wt.z * xc[i10] + wt.w * xc[i11];
        pk[j] = (short)f2bf(v);
      }
      *(short4v*)&A_lds[m * 40 + cg * 4] = pk;
    }
    {
      const short8* bp = (const short8*)(Bw + tid * KTOT + (t << 8) + c0);
      short8 b0 = bp[0], b1 = bp[1], b2 = bp[2], b3 = bp[3];
      short8* dst = (short8*)&B_lds[tid * 40];
      dst[0] = b0; dst[1] = b1; dst[2] = b2; dst[3] = b3;
    }
    __syncthreads();
    int fr = (lane >> 4) * 8;
    short8 a0 = *(short8*)&A_lds[((lane & 15)) * 40 + fr];
    short8 a1 = *(short8*)&A_lds[(16 + (lane & 15)) * 40 + fr];
#pragma unroll
    for (int nj = 0; nj < 4; ++nj) {
      short8 bfp = *(short8*)&B_lds[(n0 + nj * 16 + (lane & 15)) * 40 + fr];
      acc[0][nj] = __builtin_amdgcn_mfma_f32_16x16x32_bf16(a0, bfp, acc[0][nj], 0, 0, 0);
      acc[1][nj] = __builtin_amdgcn_mfma_f32_16x16x32_bf16(a1, bfp, acc[1][nj], 0, 0, 0);
    }
  }
  int g = lane >> 4;
#pragma unroll
  for (int mi = 0; mi < 2; ++mi) {
    int wm = w0 + mi * 16 + g * 4;
#pragma unroll
    for (int nj = 0; nj < 4; ++nj) {
      int oc = n0 + nj * 16 + (lane & 15);
      float4 vv = make_float4(acc[mi][nj][0], acc[mi][nj][1],
                              acc[mi][nj][2], acc[mi][nj][3]);
      *(float4*)&out[((n * OUTC + oc) << 12) + h * 64 + wm] = vv;
    }
  }
}

// ---------------------------------------------------------------------------
extern "C" void kernel_launch(void* const* d_in, const int* in_sizes, int n_in,
                              void* d_out, int out_size, void* d_ws, size_t ws_size,
                              hipStream_t stream) {
  const float* x     = (const float*)d_in[0];
  const float* offw  = (const float*)d_in[1];
  const float* ob    = (const float*)d_in[2];
  const float* dcn_w = (const float*)d_in[3];
  float* out = (float*)d_out;

  if (ws_size >= (size_t)WSM_END) {
    unsigned short* Bfrag  = (unsigned short*)((char*)d_ws + WSM_BFRAG);
    unsigned short* B2frag = (unsigned short*)((char*)d_ws + WSM_B2FRAG);
    unsigned short* xtb    = (unsigned short*)((char*)d_ws + WSM_XT);
    // main path: 2 launches total
    prep_main_kernel<<<580, 256, 0, stream>>>(dcn_w, offw, x, Bfrag, B2frag, xtb);
    dcn_fused_kernel<<<256, 512, 0, stream>>>(xtb, Bfrag, B2frag, ob, out);
  } else {
    unsigned short* Bw  = (unsigned short*)((char*)d_ws + WSF_BW);
    unsigned short* B2w = (unsigned short*)((char*)d_ws + WSF_B2W);
    float*          omb = (float*)((char*)d_ws + WSF_OM);
    prep_fb_kernel<<<256, 256, 0, stream>>>(dcn_w, offw, Bw, B2w);
    conv_offset_kernel<<<NB * HH, 256, 0, stream>>>(x, B2w, ob, omb);
    dcn_main_kernel<<<NB * HH * 2, 256, 0, stream>>>(x, omb, Bw, out);
  }
}